// Round 1
// baseline (852.166 us; speedup 1.0000x reference)
//
#include <hip/hip_runtime.h>

// Problem constants (fixed by the reference setup_inputs).
#define N_NODES 50000
#define N_EDGES 1600000
#define N_REL   8
#define D_IN    128
#define D_HID   128
#define D_OUT   64
#define N_POOL  256

// Capacities for the sparse dependency cone (data has fixed seed; expected
// |S|~7800, edges-into-S ~250k, edges-into-pooled ~8200; caps have >1.5x margin
// and writes are clamped so overflow cannot corrupt memory).
#define CAP_S   12288
#define CAP_E1  393216
#define CAP_E2  32768

// ---- workspace layout (element offsets, 4B elements) ----
constexpr size_t SZ_AGG1   = (size_t)N_REL * CAP_S * D_IN;        // fp32
constexpr size_t OFF_AGG1  = 0;
constexpr size_t OFF_CNT1  = OFF_AGG1 + SZ_AGG1;                  // 8*CAP_S fp32
constexpr size_t OFF_AGG2  = OFF_CNT1 + (size_t)N_REL * CAP_S;    // 8*256*128 fp32
constexpr size_t OFF_CNT2  = OFF_AGG2 + (size_t)N_REL * N_POOL * D_HID;
constexpr size_t OFF_PCLAIM= OFF_CNT2 + (size_t)N_REL * N_POOL;   // ints below
constexpr size_t OFF_PID   = OFF_PCLAIM + N_NODES;
constexpr size_t OFF_SCLAIM= OFF_PID + N_NODES;
constexpr size_t OFF_SID   = OFF_SCLAIM + N_NODES;
constexpr size_t OFF_CTR   = OFF_SID + N_NODES;                   // 8 ints
constexpr size_t ZERO_ELEMS= OFF_CTR + 8;                         // zero-init region ends here
constexpr size_t OFF_H     = ZERO_ELEMS;                          // CAP_S*128 fp32 (no zero needed)
constexpr size_t OFF_EMB   = OFF_H + (size_t)CAP_S * D_HID;       // 256*64 fp32
constexpr size_t OFF_PNODES= OFF_EMB + (size_t)N_POOL * D_OUT;
constexpr size_t OFF_SNODES= OFF_PNODES + N_POOL;
constexpr size_t OFF_E1    = OFF_SNODES + CAP_S;                  // 2*CAP_E1 ints
constexpr size_t OFF_E2    = OFF_E1 + (size_t)2 * CAP_E1;         // 2*CAP_E2 ints
constexpr size_t TOTAL_ELEMS = OFF_E2 + (size_t)2 * CAP_E2;

// counters: [0]=pCount, [1]=sCount, [2]=e1Count, [3]=e2Count

__device__ __forceinline__ void atomAddF(float* p, float v) {
  // HW fp32 atomic (global_atomic_add_f32); denormal semantics irrelevant here.
  unsafeAtomicAdd(p, v);
}

__global__ void k_zero(float4* __restrict__ p, long n4) {
  long i = (long)blockIdx.x * blockDim.x + threadIdx.x;
  long stride = (long)gridDim.x * blockDim.x;
  float4 z = {0.f, 0.f, 0.f, 0.f};
  for (; i < n4; i += stride) p[i] = z;
}

__global__ __launch_bounds__(256) void k_mark_pooled(
    const int* __restrict__ pool, int* pClaim, int* pId, int* pNodes,
    int* sClaim, int* sId, int* sNodes, int* ctr) {
  int i = threadIdx.x;
  if (i < N_POOL) {
    int node = pool[i];
    if (atomicCAS(&pClaim[node], 0, 1) == 0) {
      int id = atomicAdd(&ctr[0], 1);
      pId[node] = id + 1;
      pNodes[id] = node;
    }
    if (atomicCAS(&sClaim[node], 0, 1) == 0) {
      int id = atomicAdd(&ctr[1], 1);
      sId[node] = id + 1;
      sNodes[id] = node;
    }
  }
}

// Pass 1: find edges whose dst is pooled; record them; claim their srcs into S.
__global__ __launch_bounds__(256) void k_pass1(
    const int* __restrict__ EI, const int* __restrict__ ET,
    const int* __restrict__ pClaim, const int* __restrict__ pId,
    int* sClaim, int* sId, int* sNodes, int* ctr,
    int* __restrict__ e2, float* __restrict__ cnt2) {
  int e = blockIdx.x * blockDim.x + threadIdx.x;
  if (e >= N_EDGES) return;
  int dst = EI[N_EDGES + e];
  if (pClaim[dst]) {
    int pl = pId[dst] - 1;           // set in prior kernel -> visible
    int src = EI[e];
    int t = ET[e];
    if (atomicCAS(&sClaim[src], 0, 1) == 0) {
      int id = atomicAdd(&ctr[1], 1);
      sId[src] = id + 1;
      sNodes[id] = src;
    }
    int code = t * N_POOL + pl;
    atomAddF(&cnt2[code], 1.0f);
    int idx = atomicAdd(&ctr[3], 1);
    if (idx < CAP_E2) { e2[2*idx] = src; e2[2*idx+1] = code; }
  }
}

// Pass 2: compact all edges whose dst is in S (needed for layer-1 agg) + count.
__global__ __launch_bounds__(256) void k_pass2(
    const int* __restrict__ EI, const int* __restrict__ ET,
    const int* __restrict__ sId, int* ctr,
    int* __restrict__ e1, float* __restrict__ cnt1) {
  int e = blockIdx.x * blockDim.x + threadIdx.x;
  if (e >= N_EDGES) return;
  int dst = EI[N_EDGES + e];
  int sp = sId[dst];
  if (sp) {
    int sl = sp - 1;
    int t = ET[e];
    int src = EI[e];
    int seg = t * CAP_S + sl;
    atomAddF(&cnt1[seg], 1.0f);
    int idx = atomicAdd(&ctr[2], 1);
    if (idx < CAP_E1) { e1[2*idx] = src; e1[2*idx+1] = seg; }
  }
}

// Scatter layer-1: wave-per-edge, coalesced 128-float atomic add of x[src] into agg1[seg].
__global__ __launch_bounds__(256) void k_scatter1(
    const int* __restrict__ e1, const int* __restrict__ ctr,
    const float* __restrict__ x, float* __restrict__ agg1) {
  int n = ctr[2]; if (n > CAP_E1) n = CAP_E1;
  int nw = (int)((gridDim.x * blockDim.x) >> 6);
  int w = (int)((blockIdx.x * blockDim.x + threadIdx.x) >> 6);
  int lane = threadIdx.x & 63;
  for (; w < n; w += nw) {
    int src = e1[2*w];
    int seg = e1[2*w+1];
    const float* xr = x + (size_t)src * D_IN;
    float* ar = agg1 + (size_t)seg * D_IN;
    atomAddF(&ar[lane],      xr[lane]);
    atomAddF(&ar[lane + 64], xr[lane + 64]);
  }
}

// Layer-1 GEMM: h[s] = relu( [mean_agg(r=0..7) | x[g]] (1152) @ [W1;root1] (1152x128) + b1 )
#define TS1 8
__global__ __launch_bounds__(256) void k_gemm1(
    const float* __restrict__ x, const float* __restrict__ W1,
    const float* __restrict__ root1, const float* __restrict__ b1,
    const float* __restrict__ agg1, const float* __restrict__ cnt1,
    const int* __restrict__ sNodes, const int* __restrict__ ctr,
    float* __restrict__ h) {
  __shared__ float a[TS1][N_REL * D_IN + D_IN];   // 8 x 1152 fp32 = 36.9 KB
  __shared__ float invc[TS1][N_REL];
  int sCount = ctr[1];
  int s0 = blockIdx.x * TS1;
  if (s0 >= sCount) return;
  int tid = threadIdx.x;
  if (tid < TS1 * N_REL) {
    int si = tid >> 3, r = tid & 7;
    int s = s0 + si;
    float c = (s < sCount) ? cnt1[r * CAP_S + s] : 1.0f;
    invc[si][r] = 1.0f / fmaxf(c, 1.0f);
  }
  __syncthreads();
  for (int si = 0; si < TS1; si++) {
    int s = s0 + si;
    bool valid = (s < sCount);
    int g = valid ? sNodes[s] : 0;
    for (int k = tid; k < 1152; k += 256) {
      float v;
      if (k < 1024) {
        int r = k >> 7, d = k & 127;
        v = valid ? agg1[((size_t)(r * CAP_S + s)) * D_IN + d] * invc[si][r] : 0.0f;
      } else {
        v = x[(size_t)g * D_IN + (k - 1024)];
      }
      a[si][k] = v;
    }
  }
  __syncthreads();
  int tg = tid >> 6;       // 0..3 -> node pair (tg*2, tg*2+1); whole wave shares tg (LDS broadcast)
  int cg = tid & 63;       // col pair cg*2, cg*2+1
  float acc[2][2] = {{0.f,0.f},{0.f,0.f}};
  for (int k = 0; k < 1024; k++) {
    float2 w = ((const float2*)(W1 + (size_t)k * D_HID))[cg];
#pragma unroll
    for (int j = 0; j < 2; j++) {
      float av = a[tg*2 + j][k];
      acc[j][0] += av * w.x; acc[j][1] += av * w.y;
    }
  }
  for (int k = 0; k < 128; k++) {
    float2 w = ((const float2*)(root1 + (size_t)k * D_HID))[cg];
#pragma unroll
    for (int j = 0; j < 2; j++) {
      float av = a[tg*2 + j][1024 + k];
      acc[j][0] += av * w.x; acc[j][1] += av * w.y;
    }
  }
  int c0 = cg * 2;
#pragma unroll
  for (int j = 0; j < 2; j++) {
    int s = s0 + tg*2 + j;
    if (s < sCount) {
      h[(size_t)s * D_HID + c0]     = fmaxf(acc[j][0] + b1[c0],     0.0f);
      h[(size_t)s * D_HID + c0 + 1] = fmaxf(acc[j][1] + b1[c0 + 1], 0.0f);
    }
  }
}

// Scatter layer-2: wave-per-pooled-edge, add h[sLocal(src)] into agg2[code].
__global__ __launch_bounds__(256) void k_scatter2(
    const int* __restrict__ e2, const int* __restrict__ ctr,
    const int* __restrict__ sId, const float* __restrict__ h,
    float* __restrict__ agg2) {
  int n = ctr[3]; if (n > CAP_E2) n = CAP_E2;
  int nw = (int)((gridDim.x * blockDim.x) >> 6);
  int w = (int)((blockIdx.x * blockDim.x + threadIdx.x) >> 6);
  int lane = threadIdx.x & 63;
  for (; w < n; w += nw) {
    int src = e2[2*w];
    int code = e2[2*w+1];
    int sl = sId[src] - 1;
    const float* hr = h + (size_t)sl * D_HID;
    float* ar = agg2 + (size_t)code * D_HID;
    atomAddF(&ar[lane],      hr[lane]);
    atomAddF(&ar[lane + 64], hr[lane + 64]);
  }
}

// Layer-2 GEMM per pooled node: emb[pl] = [mean_agg2 | h[pooled]] @ [W2;root2] + b2
__global__ __launch_bounds__(64) void k_gemm2(
    const float* __restrict__ W2, const float* __restrict__ root2,
    const float* __restrict__ b2, const float* __restrict__ agg2,
    const float* __restrict__ cnt2, const int* __restrict__ pNodes,
    const int* __restrict__ sId, const int* __restrict__ ctr,
    const float* __restrict__ h, float* __restrict__ emb) {
  __shared__ float a[N_REL * D_HID + D_HID];  // 1152
  __shared__ float inv[N_REL];
  int pl = blockIdx.x;
  if (pl >= ctr[0]) return;
  int tid = threadIdx.x;
  if (tid < N_REL) inv[tid] = 1.0f / fmaxf(cnt2[tid * N_POOL + pl], 1.0f);
  __syncthreads();
  int node = pNodes[pl];
  int slp = sId[node] - 1;
  for (int k = tid; k < 1024; k += 64) {
    int r = k >> 7, d = k & 127;
    a[k] = agg2[(size_t)(r * N_POOL + pl) * D_HID + d] * inv[r];
  }
  for (int d = tid; d < 128; d += 64) a[1024 + d] = h[(size_t)slp * D_HID + d];
  __syncthreads();
  float acc = 0.0f;
  for (int k = 0; k < 1024; k++) acc += a[k] * W2[(size_t)k * D_OUT + tid];
  for (int d = 0; d < 128; d++)  acc += a[1024 + d] * root2[(size_t)d * D_OUT + tid];
  emb[(size_t)pl * D_OUT + tid] = acc + b2[tid];
}

// Weighted pooling: out[c] = sum_i ew[i]*emb[pLocal(pool[i])][c] / (sum ew + 1e-9)
__global__ __launch_bounds__(256) void k_pool(
    const float* __restrict__ x, const int* __restrict__ pool,
    const int* __restrict__ pId, const float* __restrict__ emb,
    float* __restrict__ out) {
  __shared__ float ew[N_POOL];
  __shared__ int pls[N_POOL];
  int tid = threadIdx.x;
  int node = pool[tid];
  const float* xr = x + (size_t)node * D_IN;
  ew[tid] = 4.0f * xr[0] + 1.0f * xr[1] + 2.0f * xr[2];
  pls[tid] = pId[node] - 1;
  __syncthreads();
  if (tid < D_OUT) {
    float sw = 0.0f;
    for (int j = 0; j < N_POOL; j++) sw += ew[j];
    float acc = 0.0f;
    for (int j = 0; j < N_POOL; j++) acc += ew[j] * emb[(size_t)pls[j] * D_OUT + tid];
    out[tid] = acc / (sw + 1e-9f);
  }
}

extern "C" void kernel_launch(void* const* d_in, const int* in_sizes, int n_in,
                              void* d_out, int out_size, void* d_ws, size_t ws_size,
                              hipStream_t stream) {
  const float* x     = (const float*)d_in[0];
  const int*   EI    = (const int*)  d_in[1];
  const int*   ET    = (const int*)  d_in[2];
  const int*   pool  = (const int*)  d_in[3];
  const float* W1    = (const float*)d_in[4];
  const float* root1 = (const float*)d_in[5];
  const float* b1    = (const float*)d_in[6];
  const float* W2    = (const float*)d_in[7];
  const float* root2 = (const float*)d_in[8];
  const float* b2    = (const float*)d_in[9];
  float* out = (float*)d_out;

  float* ws    = (float*)d_ws;
  float* agg1  = ws + OFF_AGG1;
  float* cnt1  = ws + OFF_CNT1;
  float* agg2  = ws + OFF_AGG2;
  float* cnt2  = ws + OFF_CNT2;
  int* pClaim  = (int*)(ws + OFF_PCLAIM);
  int* pId     = (int*)(ws + OFF_PID);
  int* sClaim  = (int*)(ws + OFF_SCLAIM);
  int* sId     = (int*)(ws + OFF_SID);
  int* ctr     = (int*)(ws + OFF_CTR);
  float* h     = ws + OFF_H;
  float* emb   = ws + OFF_EMB;
  int* pNodes  = (int*)(ws + OFF_PNODES);
  int* sNodes  = (int*)(ws + OFF_SNODES);
  int* e1      = (int*)(ws + OFF_E1);
  int* e2      = (int*)(ws + OFF_E2);

  k_zero<<<4096, 256, 0, stream>>>((float4*)ws, (long)(ZERO_ELEMS / 4));
  k_mark_pooled<<<1, 256, 0, stream>>>(pool, pClaim, pId, pNodes, sClaim, sId, sNodes, ctr);
  k_pass1<<<(N_EDGES + 255) / 256, 256, 0, stream>>>(EI, ET, pClaim, pId, sClaim, sId, sNodes, ctr, e2, cnt2);
  k_pass2<<<(N_EDGES + 255) / 256, 256, 0, stream>>>(EI, ET, sId, ctr, e1, cnt1);
  k_scatter1<<<8192, 256, 0, stream>>>(e1, ctr, x, agg1);
  k_gemm1<<<CAP_S / TS1, 256, 0, stream>>>(x, W1, root1, b1, agg1, cnt1, sNodes, ctr, h);
  k_scatter2<<<512, 256, 0, stream>>>(e2, ctr, sId, h, agg2);
  k_gemm2<<<N_POOL, 64, 0, stream>>>(W2, root2, b2, agg2, cnt2, pNodes, sId, ctr, h, emb);
  k_pool<<<1, 256, 0, stream>>>(x, pool, pId, emb, out);
}

// Round 2
// 847.777 us; speedup vs baseline: 1.0052x; 1.0052x over previous
//
#include <hip/hip_runtime.h>

// Problem constants (fixed by the reference setup_inputs).
#define N_NODES 50000
#define N_EDGES 1600000
#define N_REL   8
#define D_IN    128
#define D_HID   128
#define D_OUT   64
#define N_POOL  256

// Capacities for the sparse dependency cone (fixed seed; expected |S|~8000,
// edges-into-S ~250k, edges-into-pooled ~8200; caps have >1.5x margin and
// writes are clamped so overflow cannot corrupt memory).
#define CAP_S   12288
#define CAP_E1  393216
#define CAP_E2  32768
#define NBITW   2048   // 50000 bits -> 1563 u32, round to 2048 (8 KB, L1-resident)

// ---- workspace layout (element offsets, 4B elements) ----
constexpr size_t OFF_AGG1  = 0;                                   // 8*CAP_S*128 fp32
constexpr size_t OFF_CNT1  = OFF_AGG1 + (size_t)N_REL * CAP_S * D_IN;
constexpr size_t OFF_AGG2  = OFF_CNT1 + (size_t)N_REL * CAP_S;    // 8*256*128 fp32
constexpr size_t OFF_CNT2  = OFF_AGG2 + (size_t)N_REL * N_POOL * D_HID;
constexpr size_t OFF_PBIT  = OFF_CNT2 + (size_t)N_REL * N_POOL;   // u32 bitmap
constexpr size_t OFF_SBIT  = OFF_PBIT + NBITW;                    // u32 bitmap
constexpr size_t OFF_PID   = OFF_SBIT + NBITW;
constexpr size_t OFF_SID   = OFF_PID + N_NODES;
constexpr size_t OFF_CTR   = OFF_SID + N_NODES;                   // 8 ints
constexpr size_t ZERO_ELEMS= OFF_CTR + 8;                         // zero-init region ends here
constexpr size_t OFF_H     = ZERO_ELEMS;                          // CAP_S*128 fp32
constexpr size_t OFF_EMB   = OFF_H + (size_t)CAP_S * D_HID;       // 256*64 fp32
constexpr size_t OFF_PNODES= OFF_EMB + (size_t)N_POOL * D_OUT;
constexpr size_t OFF_SNODES= OFF_PNODES + N_POOL;
constexpr size_t OFF_E1    = OFF_SNODES + CAP_S;                  // 2*CAP_E1 ints (int2)
constexpr size_t OFF_E2    = OFF_E1 + (size_t)2 * CAP_E1;         // 2*CAP_E2 ints (int2)
constexpr size_t TOTAL_ELEMS = OFF_E2 + (size_t)2 * CAP_E2;

// counters: [0]=pCount, [1]=sCount, [2]=e1Count, [3]=e2Count

__device__ __forceinline__ void atomAddF(float* p, float v) {
  unsafeAtomicAdd(p, v);   // HW global_atomic_add_f32
}

// Wave-aggregated append: one atomic per wave instead of one per lane.
// Returns this lane's slot (only meaningful when pred is true).
__device__ __forceinline__ int waveAppend(int* ctr, bool pred) {
  unsigned long long mask = __ballot(pred);
  int total = __popcll(mask);
  if (total == 0) return -1;
  int lane = threadIdx.x & 63;
  int leader = __ffsll(mask) - 1;
  int base = 0;
  if (lane == leader) base = atomicAdd(ctr, total);
  base = __shfl(base, leader);
  return base + __popcll(mask & ((1ull << lane) - 1ull));
}

__global__ void k_zero(float4* __restrict__ p, long n4) {
  long i = (long)blockIdx.x * blockDim.x + threadIdx.x;
  long stride = (long)gridDim.x * blockDim.x;
  float4 z = {0.f, 0.f, 0.f, 0.f};
  for (; i < n4; i += stride) p[i] = z;
}

__global__ __launch_bounds__(256) void k_mark_pooled(
    const int* __restrict__ pool, unsigned* pBit, int* pId, int* pNodes,
    unsigned* sBit, int* sId, int* sNodes, int* ctr) {
  int i = threadIdx.x;
  if (i < N_POOL) {
    int node = pool[i];
    unsigned bit = 1u << (node & 31);
    if (!(atomicOr(&pBit[node >> 5], bit) & bit)) {
      int id = atomicAdd(&ctr[0], 1);
      pId[node] = id + 1;
      pNodes[id] = node;
    }
    if (!(atomicOr(&sBit[node >> 5], bit) & bit)) {
      int id = atomicAdd(&ctr[1], 1);
      sId[node] = id + 1;
      sNodes[id] = node;
    }
  }
}

// Pass 1: find edges whose dst is pooled; record them; claim their srcs into S.
__global__ __launch_bounds__(256) void k_pass1(
    const int* __restrict__ EI, const int* __restrict__ ET,
    const unsigned* __restrict__ pBit, const int* __restrict__ pId,
    unsigned* sBit, int* sId, int* sNodes, int* ctr,
    int2* __restrict__ e2, float* __restrict__ cnt2) {
  int e = blockIdx.x * blockDim.x + threadIdx.x;
  bool active = (e < N_EDGES);
  int dst = active ? EI[N_EDGES + e] : 0;
  bool hit = active && ((pBit[dst >> 5] >> (dst & 31)) & 1u);
  int idx = waveAppend(&ctr[3], hit);
  if (hit) {
    int pl = pId[dst] - 1;
    int src = EI[e];
    int t = ET[e];
    unsigned bit = 1u << (src & 31);
    if (!(atomicOr(&sBit[src >> 5], bit) & bit)) {
      int id = atomicAdd(&ctr[1], 1);
      sId[src] = id + 1;
      sNodes[id] = src;
    }
    int code = t * N_POOL + pl;
    atomAddF(&cnt2[code], 1.0f);
    if (idx < CAP_E2) e2[idx] = make_int2(src, code);
  }
}

// Pass 2: compact all edges whose dst is in S (needed for layer-1 agg) + count.
__global__ __launch_bounds__(256) void k_pass2(
    const int* __restrict__ EI, const int* __restrict__ ET,
    const unsigned* __restrict__ sBit, const int* __restrict__ sId, int* ctr,
    int2* __restrict__ e1, float* __restrict__ cnt1) {
  int e = blockIdx.x * blockDim.x + threadIdx.x;
  bool active = (e < N_EDGES);
  int dst = active ? EI[N_EDGES + e] : 0;
  bool hit = active && ((sBit[dst >> 5] >> (dst & 31)) & 1u);
  int idx = waveAppend(&ctr[2], hit);
  if (hit) {
    int sl = sId[dst] - 1;
    int t = ET[e];
    int src = EI[e];
    int seg = t * CAP_S + sl;
    atomAddF(&cnt1[seg], 1.0f);
    if (idx < CAP_E1) e1[idx] = make_int2(src, seg);
  }
}

// Scatter layer-1: wave-per-edge, coalesced 128-float atomic add of x[src] into agg1[seg].
__global__ __launch_bounds__(256) void k_scatter1(
    const int2* __restrict__ e1, const int* __restrict__ ctr,
    const float* __restrict__ x, float* __restrict__ agg1) {
  int n = ctr[2]; if (n > CAP_E1) n = CAP_E1;
  int nw = (int)((gridDim.x * blockDim.x) >> 6);
  int w = (int)((blockIdx.x * blockDim.x + threadIdx.x) >> 6);
  int lane = threadIdx.x & 63;
  for (; w < n; w += nw) {
    int2 se = e1[w];
    const float* xr = x + (size_t)se.x * D_IN;
    float* ar = agg1 + (size_t)se.y * D_IN;
    atomAddF(&ar[lane],      xr[lane]);
    atomAddF(&ar[lane + 64], xr[lane + 64]);
  }
}

// Layer-1 GEMM: h[s] = relu( [mean_agg(r=0..7) | x[g]] (1152) @ [W1;root1] (1152x128) + b1 )
#define TS1 8
__global__ __launch_bounds__(256) void k_gemm1(
    const float* __restrict__ x, const float* __restrict__ W1,
    const float* __restrict__ root1, const float* __restrict__ b1,
    const float* __restrict__ agg1, const float* __restrict__ cnt1,
    const int* __restrict__ sNodes, const int* __restrict__ ctr,
    float* __restrict__ h) {
  __shared__ float a[TS1][N_REL * D_IN + D_IN];   // 8 x 1152 fp32 = 36.9 KB
  __shared__ float invc[TS1][N_REL];
  int sCount = ctr[1];
  int s0 = blockIdx.x * TS1;
  if (s0 >= sCount) return;
  int tid = threadIdx.x;
  if (tid < TS1 * N_REL) {
    int si = tid >> 3, r = tid & 7;
    int s = s0 + si;
    float c = (s < sCount) ? cnt1[r * CAP_S + s] : 1.0f;
    invc[si][r] = 1.0f / fmaxf(c, 1.0f);
  }
  __syncthreads();
  for (int si = 0; si < TS1; si++) {
    int s = s0 + si;
    bool valid = (s < sCount);
    int g = valid ? sNodes[s] : 0;
    for (int k = tid; k < 1152; k += 256) {
      float v;
      if (k < 1024) {
        int r = k >> 7, d = k & 127;
        v = valid ? agg1[((size_t)(r * CAP_S + s)) * D_IN + d] * invc[si][r] : 0.0f;
      } else {
        v = x[(size_t)g * D_IN + (k - 1024)];
      }
      a[si][k] = v;
    }
  }
  __syncthreads();
  int tg = tid >> 6;       // 0..3 -> node pair; whole wave shares tg (LDS broadcast)
  int cg = tid & 63;       // col pair cg*2, cg*2+1
  float acc[2][2] = {{0.f,0.f},{0.f,0.f}};
  for (int k = 0; k < 1024; k++) {
    float2 w = ((const float2*)(W1 + (size_t)k * D_HID))[cg];
#pragma unroll
    for (int j = 0; j < 2; j++) {
      float av = a[tg*2 + j][k];
      acc[j][0] += av * w.x; acc[j][1] += av * w.y;
    }
  }
  for (int k = 0; k < 128; k++) {
    float2 w = ((const float2*)(root1 + (size_t)k * D_HID))[cg];
#pragma unroll
    for (int j = 0; j < 2; j++) {
      float av = a[tg*2 + j][1024 + k];
      acc[j][0] += av * w.x; acc[j][1] += av * w.y;
    }
  }
  int c0 = cg * 2;
#pragma unroll
  for (int j = 0; j < 2; j++) {
    int s = s0 + tg*2 + j;
    if (s < sCount) {
      h[(size_t)s * D_HID + c0]     = fmaxf(acc[j][0] + b1[c0],     0.0f);
      h[(size_t)s * D_HID + c0 + 1] = fmaxf(acc[j][1] + b1[c0 + 1], 0.0f);
    }
  }
}

// Scatter layer-2: wave-per-pooled-edge, add h[sLocal(src)] into agg2[code].
__global__ __launch_bounds__(256) void k_scatter2(
    const int2* __restrict__ e2, const int* __restrict__ ctr,
    const int* __restrict__ sId, const float* __restrict__ h,
    float* __restrict__ agg2) {
  int n = ctr[3]; if (n > CAP_E2) n = CAP_E2;
  int nw = (int)((gridDim.x * blockDim.x) >> 6);
  int w = (int)((blockIdx.x * blockDim.x + threadIdx.x) >> 6);
  int lane = threadIdx.x & 63;
  for (; w < n; w += nw) {
    int2 se = e2[w];
    int sl = sId[se.x] - 1;
    const float* hr = h + (size_t)sl * D_HID;
    float* ar = agg2 + (size_t)se.y * D_HID;
    atomAddF(&ar[lane],      hr[lane]);
    atomAddF(&ar[lane + 64], hr[lane + 64]);
  }
}

// Layer-2 GEMM per pooled node: emb[pl] = [mean_agg2 | h[pooled]] @ [W2;root2] + b2
__global__ __launch_bounds__(64) void k_gemm2(
    const float* __restrict__ W2, const float* __restrict__ root2,
    const float* __restrict__ b2, const float* __restrict__ agg2,
    const float* __restrict__ cnt2, const int* __restrict__ pNodes,
    const int* __restrict__ sId, const int* __restrict__ ctr,
    const float* __restrict__ h, float* __restrict__ emb) {
  __shared__ float a[N_REL * D_HID + D_HID];  // 1152
  __shared__ float inv[N_REL];
  int pl = blockIdx.x;
  if (pl >= ctr[0]) return;
  int tid = threadIdx.x;
  if (tid < N_REL) inv[tid] = 1.0f / fmaxf(cnt2[tid * N_POOL + pl], 1.0f);
  __syncthreads();
  int node = pNodes[pl];
  int slp = sId[node] - 1;
  for (int k = tid; k < 1024; k += 64) {
    int r = k >> 7, d = k & 127;
    a[k] = agg2[(size_t)(r * N_POOL + pl) * D_HID + d] * inv[r];
  }
  for (int d = tid; d < 128; d += 64) a[1024 + d] = h[(size_t)slp * D_HID + d];
  __syncthreads();
  float acc = 0.0f;
  for (int k = 0; k < 1024; k++) acc += a[k] * W2[(size_t)k * D_OUT + tid];
  for (int d = 0; d < 128; d++)  acc += a[1024 + d] * root2[(size_t)d * D_OUT + tid];
  emb[(size_t)pl * D_OUT + tid] = acc + b2[tid];
}

// Weighted pooling: out[c] = sum_i ew[i]*emb[pLocal(pool[i])][c] / (sum ew + 1e-9)
__global__ __launch_bounds__(256) void k_pool(
    const float* __restrict__ x, const int* __restrict__ pool,
    const int* __restrict__ pId, const float* __restrict__ emb,
    float* __restrict__ out) {
  __shared__ float ew[N_POOL];
  __shared__ int pls[N_POOL];
  int tid = threadIdx.x;
  int node = pool[tid];
  const float* xr = x + (size_t)node * D_IN;
  ew[tid] = 4.0f * xr[0] + 1.0f * xr[1] + 2.0f * xr[2];
  pls[tid] = pId[node] - 1;
  __syncthreads();
  if (tid < D_OUT) {
    float sw = 0.0f;
    for (int j = 0; j < N_POOL; j++) sw += ew[j];
    float acc = 0.0f;
    for (int j = 0; j < N_POOL; j++) acc += ew[j] * emb[(size_t)pls[j] * D_OUT + tid];
    out[tid] = acc / (sw + 1e-9f);
  }
}

extern "C" void kernel_launch(void* const* d_in, const int* in_sizes, int n_in,
                              void* d_out, int out_size, void* d_ws, size_t ws_size,
                              hipStream_t stream) {
  const float* x     = (const float*)d_in[0];
  const int*   EI    = (const int*)  d_in[1];
  const int*   ET    = (const int*)  d_in[2];
  const int*   pool  = (const int*)  d_in[3];
  const float* W1    = (const float*)d_in[4];
  const float* root1 = (const float*)d_in[5];
  const float* b1    = (const float*)d_in[6];
  const float* W2    = (const float*)d_in[7];
  const float* root2 = (const float*)d_in[8];
  const float* b2    = (const float*)d_in[9];
  float* out = (float*)d_out;

  float* ws    = (float*)d_ws;
  float* agg1  = ws + OFF_AGG1;
  float* cnt1  = ws + OFF_CNT1;
  float* agg2  = ws + OFF_AGG2;
  float* cnt2  = ws + OFF_CNT2;
  unsigned* pBit = (unsigned*)(ws + OFF_PBIT);
  unsigned* sBit = (unsigned*)(ws + OFF_SBIT);
  int* pId     = (int*)(ws + OFF_PID);
  int* sId     = (int*)(ws + OFF_SID);
  int* ctr     = (int*)(ws + OFF_CTR);
  float* h     = ws + OFF_H;
  float* emb   = ws + OFF_EMB;
  int* pNodes  = (int*)(ws + OFF_PNODES);
  int* sNodes  = (int*)(ws + OFF_SNODES);
  int2* e1     = (int2*)(ws + OFF_E1);
  int2* e2     = (int2*)(ws + OFF_E2);

  k_zero<<<4096, 256, 0, stream>>>((float4*)ws, (long)(ZERO_ELEMS / 4));
  k_mark_pooled<<<1, 256, 0, stream>>>(pool, pBit, pId, pNodes, sBit, sId, sNodes, ctr);
  k_pass1<<<(N_EDGES + 255) / 256, 256, 0, stream>>>(EI, ET, pBit, pId, sBit, sId, sNodes, ctr, e2, cnt2);
  k_pass2<<<(N_EDGES + 255) / 256, 256, 0, stream>>>(EI, ET, sBit, sId, ctr, e1, cnt1);
  k_scatter1<<<8192, 256, 0, stream>>>(e1, ctr, x, agg1);
  k_gemm1<<<CAP_S / TS1, 256, 0, stream>>>(x, W1, root1, b1, agg1, cnt1, sNodes, ctr, h);
  k_scatter2<<<512, 256, 0, stream>>>(e2, ctr, sId, h, agg2);
  k_gemm2<<<N_POOL, 64, 0, stream>>>(W2, root2, b2, agg2, cnt2, pNodes, sId, ctr, h, emb);
  k_pool<<<1, 256, 0, stream>>>(x, pool, pId, emb, out);
}

// Round 3
// 445.922 us; speedup vs baseline: 1.9110x; 1.9012x over previous
//
#include <hip/hip_runtime.h>

// Problem constants (fixed by the reference setup_inputs).
#define N_NODES 50000
#define N_EDGES 1600000
#define N_REL   8
#define D_IN    128
#define D_HID   128
#define D_OUT   64
#define N_POOL  256

// Sparse dependency cone capacities (fixed seed; expected |S|~7700,
// edges-into-S ~250k; CAP_S has >1.5x margin, writes clamped).
#define CAP_S   12288
#define NBITW   2048   // 50000 bits -> 1563 u32, rounded (8 KB, L1-resident)
#define CHUNK   1024   // edges per block-iteration in fused scan+scatter

// ---- workspace layout (element offsets, 4B elements) ----
// Zero-initialized region first (harness poisons ws with 0xAA):
constexpr size_t OFF_AGG1  = 0;                                   // 8*CAP_S*128 fp32
constexpr size_t OFF_CNT1  = OFF_AGG1 + (size_t)N_REL * CAP_S * D_IN;
constexpr size_t OFF_AGG2  = OFF_CNT1 + (size_t)N_REL * CAP_S;    // 8*256*128 fp32
constexpr size_t OFF_CNT2  = OFF_AGG2 + (size_t)N_REL * N_POOL * D_HID;
constexpr size_t OFF_PBIT  = OFF_CNT2 + (size_t)N_REL * N_POOL;   // u32 bitmap
constexpr size_t OFF_SBIT  = OFF_PBIT + NBITW;                    // u32 bitmap
constexpr size_t OFF_CTR   = OFF_SBIT + NBITW;                    // 8 ints
constexpr size_t ZERO_ELEMS= OFF_CTR + 8;
// Write-before-read region (no zeroing needed):
constexpr size_t OFF_PID   = ZERO_ELEMS;
constexpr size_t OFF_SID   = OFF_PID + N_NODES;
constexpr size_t OFF_H     = OFF_SID + N_NODES;                   // CAP_S*128 fp32
constexpr size_t OFF_EMB   = OFF_H + (size_t)CAP_S * D_HID;       // 256*64 fp32
constexpr size_t OFF_PNODES= OFF_EMB + (size_t)N_POOL * D_OUT;
constexpr size_t OFF_SNODES= OFF_PNODES + N_POOL;
constexpr size_t TOTAL_ELEMS = OFF_SNODES + CAP_S;

// counters: [0]=pCount, [1]=sCount

__device__ __forceinline__ void atomAddF(float* p, float v) {
  unsafeAtomicAdd(p, v);   // HW global_atomic_add_f32
}

__global__ void k_zero(float4* __restrict__ p, long n4) {
  long i = (long)blockIdx.x * blockDim.x + threadIdx.x;
  long stride = (long)gridDim.x * blockDim.x;
  float4 z = {0.f, 0.f, 0.f, 0.f};
  for (; i < n4; i += stride) p[i] = z;
}

// Mark pooled nodes: pBit + pId/pNodes compaction (256-long chain, ~3us), sBit.
__global__ __launch_bounds__(256) void k_mark_pooled(
    const int* __restrict__ pool, unsigned* pBit, int* pId, int* pNodes,
    unsigned* sBit, int* ctr) {
  int node = pool[threadIdx.x];
  unsigned bit = 1u << (node & 31);
  if (!(atomicOr(&pBit[node >> 5], bit) & bit)) {
    int id = atomicAdd(&ctr[0], 1);
    pId[node] = id + 1;
    pNodes[id] = node;
  }
  atomicOr(&sBit[node >> 5], bit);
}

// Pass 1: mark sources of pooled-dst edges into sBit. No counters, no lists.
__global__ __launch_bounds__(256) void k_pass1(
    const int* __restrict__ EI, const unsigned* __restrict__ pBit,
    unsigned* sBit) {
  int e = blockIdx.x * blockDim.x + threadIdx.x;
  if (e >= N_EDGES) return;
  int dst = EI[N_EDGES + e];
  if ((pBit[dst >> 5] >> (dst & 31)) & 1u) {
    int src = EI[e];
    atomicOr(&sBit[src >> 5], 1u << (src & 31));
  }
}

// Number the S set: one global atomic per wave over node space (~780 total).
__global__ __launch_bounds__(256) void k_compactS(
    const unsigned* __restrict__ sBit, int* sId, int* sNodes, int* ctr) {
  int node = blockIdx.x * 256 + threadIdx.x;
  bool pred = (node < N_NODES) && ((sBit[node >> 5] >> (node & 31)) & 1u);
  unsigned long long mask = __ballot(pred);
  if (mask == 0ull) return;
  int lane = threadIdx.x & 63;
  int leader = __ffsll(mask) - 1;
  int base = 0;
  if (lane == leader) base = atomicAdd(&ctr[1], __popcll(mask));
  base = __shfl(base, leader);
  if (pred) {
    int id = base + __popcll(mask & ((1ull << lane) - 1ull));
    if (id < CAP_S) { sId[node] = id + 1; sNodes[id] = node; }
    else sId[node] = 0;
  }
}

// Fused pass2 + scatter1: per 1024-edge chunk, collect hits in LDS (block-local
// atomics, no global chain), then 4 waves cooperatively scatter x[src] into
// agg1[seg] with coalesced 64-lane fp32 atomics.
__global__ __launch_bounds__(256) void k_pass2_scatter(
    const int* __restrict__ EI, const int* __restrict__ ET,
    const unsigned* __restrict__ sBit, const int* __restrict__ sId,
    const float* __restrict__ x, float* __restrict__ agg1,
    float* __restrict__ cnt1) {
  __shared__ int2 hits[CHUNK];
  __shared__ int lcnt;
  int tid = threadIdx.x;
  int nChunks = (N_EDGES + CHUNK - 1) / CHUNK;
  for (int c = blockIdx.x; c < nChunks; c += gridDim.x) {
    if (tid == 0) lcnt = 0;
    __syncthreads();
    int base = c * CHUNK;
    for (int i = tid; i < CHUNK; i += 256) {
      int e = base + i;
      if (e < N_EDGES) {
        int dst = EI[N_EDGES + e];
        if ((sBit[dst >> 5] >> (dst & 31)) & 1u) {
          int sp = sId[dst];
          if (sp > 0) {
            int seg = ET[e] * CAP_S + (sp - 1);
            atomAddF(&cnt1[seg], 1.0f);
            int p = atomicAdd(&lcnt, 1);
            hits[p] = make_int2(EI[e], seg);
          }
        }
      }
    }
    __syncthreads();
    int nh = lcnt;
    int wid = tid >> 6, lane = tid & 63;
    for (int i = wid; i < nh; i += 4) {
      int2 sc = hits[i];
      const float* xr = x + (size_t)sc.x * D_IN;
      float* ar = agg1 + (size_t)sc.y * D_IN;
      atomAddF(&ar[lane],      xr[lane]);
      atomAddF(&ar[lane + 64], xr[lane + 64]);
    }
    __syncthreads();
  }
}

// Layer-1 GEMM: h[s] = relu( [mean_agg(r=0..7) | x[g]] (1152) @ [W1;root1] + b1 )
#define TS1 8
__global__ __launch_bounds__(256) void k_gemm1(
    const float* __restrict__ x, const float* __restrict__ W1,
    const float* __restrict__ root1, const float* __restrict__ b1,
    const float* __restrict__ agg1, const float* __restrict__ cnt1,
    const int* __restrict__ sNodes, const int* __restrict__ ctr,
    float* __restrict__ h) {
  __shared__ float a[TS1][N_REL * D_IN + D_IN];   // 8 x 1152 fp32 = 36.9 KB
  __shared__ float invc[TS1][N_REL];
  int sCount = ctr[1];
  int s0 = blockIdx.x * TS1;
  if (s0 >= sCount) return;
  int tid = threadIdx.x;
  if (tid < TS1 * N_REL) {
    int si = tid >> 3, r = tid & 7;
    int s = s0 + si;
    float c = (s < sCount) ? cnt1[r * CAP_S + s] : 1.0f;
    invc[si][r] = 1.0f / fmaxf(c, 1.0f);
  }
  __syncthreads();
  for (int si = 0; si < TS1; si++) {
    int s = s0 + si;
    bool valid = (s < sCount);
    int g = valid ? sNodes[s] : 0;
    for (int k = tid; k < 1152; k += 256) {
      float v;
      if (k < 1024) {
        int r = k >> 7, d = k & 127;
        v = valid ? agg1[((size_t)(r * CAP_S + s)) * D_IN + d] * invc[si][r] : 0.0f;
      } else {
        v = x[(size_t)g * D_IN + (k - 1024)];
      }
      a[si][k] = v;
    }
  }
  __syncthreads();
  int tg = tid >> 6;       // wave-uniform node-pair selector (LDS broadcast)
  int cg = tid & 63;       // col pair cg*2, cg*2+1
  float acc[2][2] = {{0.f,0.f},{0.f,0.f}};
  for (int k = 0; k < 1024; k++) {
    float2 w = ((const float2*)(W1 + (size_t)k * D_HID))[cg];
#pragma unroll
    for (int j = 0; j < 2; j++) {
      float av = a[tg*2 + j][k];
      acc[j][0] += av * w.x; acc[j][1] += av * w.y;
    }
  }
  for (int k = 0; k < 128; k++) {
    float2 w = ((const float2*)(root1 + (size_t)k * D_HID))[cg];
#pragma unroll
    for (int j = 0; j < 2; j++) {
      float av = a[tg*2 + j][1024 + k];
      acc[j][0] += av * w.x; acc[j][1] += av * w.y;
    }
  }
  int c0 = cg * 2;
#pragma unroll
  for (int j = 0; j < 2; j++) {
    int s = s0 + tg*2 + j;
    if (s < sCount) {
      h[(size_t)s * D_HID + c0]     = fmaxf(acc[j][0] + b1[c0],     0.0f);
      h[(size_t)s * D_HID + c0 + 1] = fmaxf(acc[j][1] + b1[c0 + 1], 0.0f);
    }
  }
}

// Fused edge re-scan + layer-2 scatter: hits are pooled-dst edges (~8k);
// scatter h[sId[src]] into agg2[code], count cnt2.
__global__ __launch_bounds__(256) void k_scatter2(
    const int* __restrict__ EI, const int* __restrict__ ET,
    const unsigned* __restrict__ pBit, const int* __restrict__ pId,
    const int* __restrict__ sId, const float* __restrict__ h,
    float* __restrict__ agg2, float* __restrict__ cnt2) {
  __shared__ int2 hits[CHUNK];
  __shared__ int lcnt;
  int tid = threadIdx.x;
  int nChunks = (N_EDGES + CHUNK - 1) / CHUNK;
  for (int c = blockIdx.x; c < nChunks; c += gridDim.x) {
    if (tid == 0) lcnt = 0;
    __syncthreads();
    int base = c * CHUNK;
    for (int i = tid; i < CHUNK; i += 256) {
      int e = base + i;
      if (e < N_EDGES) {
        int dst = EI[N_EDGES + e];
        if ((pBit[dst >> 5] >> (dst & 31)) & 1u) {
          int pl = pId[dst] - 1;
          int sl = sId[EI[e]] - 1;
          int code = ET[e] * N_POOL + pl;
          atomAddF(&cnt2[code], 1.0f);
          int p = atomicAdd(&lcnt, 1);
          hits[p] = make_int2(sl, code);
        }
      }
    }
    __syncthreads();
    int nh = lcnt;
    int wid = tid >> 6, lane = tid & 63;
    for (int i = wid; i < nh; i += 4) {
      int2 sc = hits[i];
      const float* hr = h + (size_t)sc.x * D_HID;
      float* ar = agg2 + (size_t)sc.y * D_HID;
      atomAddF(&ar[lane],      hr[lane]);
      atomAddF(&ar[lane + 64], hr[lane + 64]);
    }
    __syncthreads();
  }
}

// Layer-2 GEMM per pooled node: emb[pl] = [mean_agg2 | h[pooled]] @ [W2;root2] + b2
__global__ __launch_bounds__(64) void k_gemm2(
    const float* __restrict__ W2, const float* __restrict__ root2,
    const float* __restrict__ b2, const float* __restrict__ agg2,
    const float* __restrict__ cnt2, const int* __restrict__ pNodes,
    const int* __restrict__ sId, const int* __restrict__ ctr,
    const float* __restrict__ h, float* __restrict__ emb) {
  __shared__ float a[N_REL * D_HID + D_HID];  // 1152
  __shared__ float inv[N_REL];
  int pl = blockIdx.x;
  if (pl >= ctr[0]) return;
  int tid = threadIdx.x;
  if (tid < N_REL) inv[tid] = 1.0f / fmaxf(cnt2[tid * N_POOL + pl], 1.0f);
  __syncthreads();
  int node = pNodes[pl];
  int slp = sId[node] - 1;
  for (int k = tid; k < 1024; k += 64) {
    int r = k >> 7, d = k & 127;
    a[k] = agg2[(size_t)(r * N_POOL + pl) * D_HID + d] * inv[r];
  }
  for (int d = tid; d < 128; d += 64) a[1024 + d] = h[(size_t)slp * D_HID + d];
  __syncthreads();
  float acc = 0.0f;
  for (int k = 0; k < 1024; k++) acc += a[k] * W2[(size_t)k * D_OUT + tid];
  for (int d = 0; d < 128; d++)  acc += a[1024 + d] * root2[(size_t)d * D_OUT + tid];
  emb[(size_t)pl * D_OUT + tid] = acc + b2[tid];
}

// Weighted pooling.
__global__ __launch_bounds__(256) void k_pool(
    const float* __restrict__ x, const int* __restrict__ pool,
    const int* __restrict__ pId, const float* __restrict__ emb,
    float* __restrict__ out) {
  __shared__ float ew[N_POOL];
  __shared__ int pls[N_POOL];
  int tid = threadIdx.x;
  int node = pool[tid];
  const float* xr = x + (size_t)node * D_IN;
  ew[tid] = 4.0f * xr[0] + 1.0f * xr[1] + 2.0f * xr[2];
  pls[tid] = pId[node] - 1;
  __syncthreads();
  if (tid < D_OUT) {
    float sw = 0.0f;
    for (int j = 0; j < N_POOL; j++) sw += ew[j];
    float acc = 0.0f;
    for (int j = 0; j < N_POOL; j++) acc += ew[j] * emb[(size_t)pls[j] * D_OUT + tid];
    out[tid] = acc / (sw + 1e-9f);
  }
}

extern "C" void kernel_launch(void* const* d_in, const int* in_sizes, int n_in,
                              void* d_out, int out_size, void* d_ws, size_t ws_size,
                              hipStream_t stream) {
  const float* x     = (const float*)d_in[0];
  const int*   EI    = (const int*)  d_in[1];
  const int*   ET    = (const int*)  d_in[2];
  const int*   pool  = (const int*)  d_in[3];
  const float* W1    = (const float*)d_in[4];
  const float* root1 = (const float*)d_in[5];
  const float* b1    = (const float*)d_in[6];
  const float* W2    = (const float*)d_in[7];
  const float* root2 = (const float*)d_in[8];
  const float* b2    = (const float*)d_in[9];
  float* out = (float*)d_out;

  float* ws    = (float*)d_ws;
  float* agg1  = ws + OFF_AGG1;
  float* cnt1  = ws + OFF_CNT1;
  float* agg2  = ws + OFF_AGG2;
  float* cnt2  = ws + OFF_CNT2;
  unsigned* pBit = (unsigned*)(ws + OFF_PBIT);
  unsigned* sBit = (unsigned*)(ws + OFF_SBIT);
  int* ctr     = (int*)(ws + OFF_CTR);
  int* pId     = (int*)(ws + OFF_PID);
  int* sId     = (int*)(ws + OFF_SID);
  float* h     = ws + OFF_H;
  float* emb   = ws + OFF_EMB;
  int* pNodes  = (int*)(ws + OFF_PNODES);
  int* sNodes  = (int*)(ws + OFF_SNODES);

  k_zero<<<4096, 256, 0, stream>>>((float4*)ws, (long)((ZERO_ELEMS + 3) / 4));
  k_mark_pooled<<<1, 256, 0, stream>>>(pool, pBit, pId, pNodes, sBit, ctr);
  k_pass1<<<(N_EDGES + 255) / 256, 256, 0, stream>>>(EI, pBit, sBit);
  k_compactS<<<(N_NODES + 255) / 256, 256, 0, stream>>>(sBit, sId, sNodes, ctr);
  k_pass2_scatter<<<1024, 256, 0, stream>>>(EI, ET, sBit, sId, x, agg1, cnt1);
  k_gemm1<<<CAP_S / TS1, 256, 0, stream>>>(x, W1, root1, b1, agg1, cnt1, sNodes, ctr, h);
  k_scatter2<<<1024, 256, 0, stream>>>(EI, ET, pBit, pId, sId, h, agg2, cnt2);
  k_gemm2<<<N_POOL, 64, 0, stream>>>(W2, root2, b2, agg2, cnt2, pNodes, sId, ctr, h, emb);
  k_pool<<<1, 256, 0, stream>>>(x, pool, pId, emb, out);
}

// Round 4
// 288.619 us; speedup vs baseline: 2.9526x; 1.5450x over previous
//
#include <hip/hip_runtime.h>

// Problem constants (fixed by the reference setup_inputs).
#define N_NODES 50000
#define N_EDGES 1600000
#define N_REL   8
#define D_IN    128
#define D_HID   128
#define D_OUT   64
#define N_POOL  256

// Sparse dependency cone capacities (fixed seed; expected |S|~7700,
// edges-into-S ~250k; CAP_S has >1.5x margin, writes clamped).
#define CAP_S   12288
#define CAP_E1  393216
#define NSEG    (N_REL * CAP_S)     // 98304 segments (r, s-local)
#define CHUNK   1024

typedef short v8s __attribute__((ext_vector_type(8)));
typedef float v4f __attribute__((ext_vector_type(4)));

// ---- workspace layout (element offsets, 4B units) ----
// Zero-initialized region:
constexpr size_t OFF_CNTA   = 0;                       // NSEG int   (edge counts per seg)
constexpr size_t OFF_FILLC  = OFF_CNTA + NSEG;         // NSEG int   (fill cursors)
constexpr size_t OFF_AGG2   = OFF_FILLC + NSEG;        // 8*256*128 fp32
constexpr size_t OFF_CNT2   = OFF_AGG2 + (size_t)N_REL * N_POOL * D_HID;  // 2048 fp32
constexpr size_t OFF_PBIT   = OFF_CNT2 + (size_t)N_REL * N_POOL;          // 2048 u32
constexpr size_t OFF_SBIT   = OFF_PBIT + 2048;         // 2048 u32
constexpr size_t OFF_CTR    = OFF_SBIT + 2048;         // 8 int
constexpr size_t ZERO_ELEMS = OFF_CTR + 8;             // = 464,904 (div by 4)
// Write-before-read region:
constexpr size_t OFF_PTRA   = ZERO_ELEMS;              // NSEG int (exclusive scan)
constexpr size_t OFF_BSUM   = OFF_PTRA + NSEG;         // 128 int
constexpr size_t OFF_BOFF   = OFF_BSUM + 128;          // 128 int
constexpr size_t OFF_PID    = OFF_BOFF + 128;          // N_NODES int
constexpr size_t OFF_SID    = OFF_PID + N_NODES;       // N_NODES int
constexpr size_t OFF_PNODES = OFF_SID + N_NODES;       // 256 int
constexpr size_t OFF_SNODES = OFF_PNODES + N_POOL;     // CAP_S int
constexpr size_t OFF_SRCSLOT= OFF_SNODES + CAP_S;      // CAP_E1 int
constexpr size_t OFF_AGG1B  = OFF_SRCSLOT + CAP_E1;    // NSEG*128 bf16 (mean agg, bf16)
constexpr size_t OFF_XB     = OFF_AGG1B + (size_t)NSEG * 128 / 2;   // CAP_S*128 bf16
constexpr size_t OFF_WT     = OFF_XB + (size_t)CAP_S * 128 / 2;     // 1152*128 bf16 (frag-packed)
constexpr size_t OFF_H      = OFF_WT + (size_t)1152 * 128 / 2;      // CAP_S*128 fp32
constexpr size_t OFF_EMB    = OFF_H + (size_t)CAP_S * D_HID;        // 256*64 fp32
constexpr size_t TOTAL_ELEMS= OFF_EMB + (size_t)N_POOL * D_OUT;     // ~9.8M elems (39 MB)

// counters: [0]=pCount, [1]=sCount

__device__ __forceinline__ void atomAddF(float* p, float v) { unsafeAtomicAdd(p, v); }

__device__ __forceinline__ unsigned short f2bf(float f) {   // RNE fp32 -> bf16
  union { float f; unsigned u; } v; v.f = f;
  unsigned r = v.u + 0x7FFFu + ((v.u >> 16) & 1u);
  return (unsigned short)(r >> 16);
}

__global__ void k_zero(float4* __restrict__ p, long n4) {
  long i = (long)blockIdx.x * blockDim.x + threadIdx.x;
  long stride = (long)gridDim.x * blockDim.x;
  float4 z = {0.f, 0.f, 0.f, 0.f};
  for (; i < n4; i += stride) p[i] = z;
}

__global__ __launch_bounds__(256) void k_mark_pooled(
    const int* __restrict__ pool, unsigned* pBit, int* pId, int* pNodes,
    unsigned* sBit, int* ctr) {
  int node = pool[threadIdx.x];
  unsigned bit = 1u << (node & 31);
  if (!(atomicOr(&pBit[node >> 5], bit) & bit)) {
    int id = atomicAdd(&ctr[0], 1);
    pId[node] = id + 1;
    pNodes[id] = node;
  }
  atomicOr(&sBit[node >> 5], bit);
}

// Pass 1: mark sources of pooled-dst edges into sBit (int4-vectorized dst scan).
__global__ __launch_bounds__(256) void k_pass1(
    const int* __restrict__ EI, const unsigned* __restrict__ pBit, unsigned* sBit) {
  int idx = blockIdx.x * 256 + threadIdx.x;
  if (idx >= N_EDGES / 4) return;
  int4 d4 = ((const int4*)(EI + N_EDGES))[idx];
  int d[4] = {d4.x, d4.y, d4.z, d4.w};
#pragma unroll
  for (int i = 0; i < 4; i++) {
    int dst = d[i];
    if ((pBit[dst >> 5] >> (dst & 31)) & 1u) {
      int src = EI[idx * 4 + i];
      atomicOr(&sBit[src >> 5], 1u << (src & 31));
    }
  }
}

// Number the S set: one global atomic per wave over node space.
__global__ __launch_bounds__(256) void k_compactS(
    const unsigned* __restrict__ sBit, int* sId, int* sNodes, int* ctr) {
  int node = blockIdx.x * 256 + threadIdx.x;
  bool pred = (node < N_NODES) && ((sBit[node >> 5] >> (node & 31)) & 1u);
  unsigned long long mask = __ballot(pred);
  if (mask == 0ull) return;
  int lane = threadIdx.x & 63;
  int leader = __ffsll(mask) - 1;
  int base = 0;
  if (lane == leader) base = atomicAdd(&ctr[1], __popcll(mask));
  base = __shfl(base, leader);
  if (pred) {
    int id = base + __popcll(mask & ((1ull << lane) - 1ull));
    if (id < CAP_S) { sId[node] = id + 1; sNodes[id] = node; }
    else sId[node] = 0;
  }
}

// Count edges per (rel, s-local) segment.
__global__ __launch_bounds__(256) void k_count(
    const int* __restrict__ EI, const int* __restrict__ ET,
    const unsigned* __restrict__ sBit, const int* __restrict__ sId,
    int* __restrict__ cntArr) {
  int idx = blockIdx.x * 256 + threadIdx.x;
  if (idx >= N_EDGES / 4) return;
  int4 d4 = ((const int4*)(EI + N_EDGES))[idx];
  int4 t4 = ((const int4*)ET)[idx];
  int d[4] = {d4.x, d4.y, d4.z, d4.w};
  int t[4] = {t4.x, t4.y, t4.z, t4.w};
#pragma unroll
  for (int i = 0; i < 4; i++) {
    int dst = d[i];
    if ((sBit[dst >> 5] >> (dst & 31)) & 1u) {
      int sp = sId[dst];
      if (sp > 0) atomicAdd(&cntArr[t[i] * CAP_S + (sp - 1)], 1);
    }
  }
}

// Prefix scan over NSEG=98304 counts: A (per-1024-block scan), B (scan of 96
// block sums), C (add block offsets). ptrA = exclusive scan; cntArr preserved.
__global__ __launch_bounds__(256) void k_scanA(
    const int* __restrict__ cntArr, int* __restrict__ ptrA, int* __restrict__ bsum) {
  __shared__ int sd[256];
  int t = threadIdx.x;
  int base = blockIdx.x * 1024 + t * 4;
  int4 c4 = ((const int4*)cntArr)[base >> 2];
  int ts = c4.x + c4.y + c4.z + c4.w;
  sd[t] = ts; __syncthreads();
  for (int off = 1; off < 256; off <<= 1) {
    int v = (t >= off) ? sd[t - off] : 0;
    __syncthreads();
    sd[t] += v;
    __syncthreads();
  }
  int excl = sd[t] - ts;
  int4 o; o.x = excl; o.y = excl + c4.x; o.z = o.y + c4.y; o.w = o.z + c4.z;
  ((int4*)ptrA)[base >> 2] = o;
  if (t == 255) bsum[blockIdx.x] = sd[255];
}

__global__ __launch_bounds__(128) void k_scanB(
    const int* __restrict__ bsum, int* __restrict__ boff) {
  __shared__ int sd[128];
  int t = threadIdx.x;
  int v = (t < 96) ? bsum[t] : 0;
  sd[t] = v; __syncthreads();
  for (int off = 1; off < 128; off <<= 1) {
    int u = (t >= off) ? sd[t - off] : 0;
    __syncthreads();
    sd[t] += u;
    __syncthreads();
  }
  if (t < 96) boff[t] = sd[t] - v;
}

__global__ __launch_bounds__(256) void k_scanC(
    int* __restrict__ ptrA, const int* __restrict__ boff) {
  int i = blockIdx.x * 256 + threadIdx.x;
  if (i < NSEG) ptrA[i] += boff[i >> 10];
}

// Fill CSR edge slots: srcSlot[ptrA[seg] + cursor] = src.
__global__ __launch_bounds__(256) void k_fill(
    const int* __restrict__ EI, const int* __restrict__ ET,
    const unsigned* __restrict__ sBit, const int* __restrict__ sId,
    const int* __restrict__ ptrA, int* __restrict__ fillCtr,
    int* __restrict__ srcSlot) {
  int idx = blockIdx.x * 256 + threadIdx.x;
  if (idx >= N_EDGES / 4) return;
  int4 d4 = ((const int4*)(EI + N_EDGES))[idx];
  int4 t4 = ((const int4*)ET)[idx];
  int4 s4 = ((const int4*)EI)[idx];
  int d[4] = {d4.x, d4.y, d4.z, d4.w};
  int t[4] = {t4.x, t4.y, t4.z, t4.w};
  int s[4] = {s4.x, s4.y, s4.z, s4.w};
#pragma unroll
  for (int i = 0; i < 4; i++) {
    int dst = d[i];
    if ((sBit[dst >> 5] >> (dst & 31)) & 1u) {
      int sp = sId[dst];
      if (sp > 0) {
        int seg = t[i] * CAP_S + (sp - 1);
        int slot = ptrA[seg] + atomicAdd(&fillCtr[seg], 1);
        if (slot < CAP_E1) srcSlot[slot] = s[i];
      }
    }
  }
}

// Gather-reduce: one wave per segment; sum x[src] rows in registers, write
// the MEAN directly in bf16 (feeds MFMA A-fragments). No atomics.
__global__ __launch_bounds__(256) void k_gather(
    const int* __restrict__ ptrA, const int* __restrict__ cntArr,
    const int* __restrict__ srcSlot, const float* __restrict__ x,
    const int* __restrict__ ctr, unsigned short* __restrict__ agg1b) {
  int w = (blockIdx.x << 2) + (threadIdx.x >> 6);
  int sCount = ctr[1];
  int s = w % CAP_S;
  if (s >= sCount) return;
  int lane = threadIdx.x & 63;
  int begin = ptrA[w];
  int cnt = cntArr[w];
  float a0 = 0.f, a1 = 0.f;
  for (int i = 0; i < cnt; i++) {
    int src = srcSlot[begin + i];
    const float* xr = x + (size_t)src * D_IN;
    a0 += xr[lane];
    a1 += xr[lane + 64];
  }
  float inv = 1.0f / fmaxf((float)cnt, 1.0f);
  agg1b[(size_t)w * 128 + lane]      = f2bf(a0 * inv);
  agg1b[(size_t)w * 128 + 64 + lane] = f2bf(a1 * inv);
}

// Convert x rows of S-nodes to bf16 (the root-term part of A).
__global__ __launch_bounds__(256) void k_xconvert(
    const float* __restrict__ x, const int* __restrict__ sNodes,
    const int* __restrict__ ctr, unsigned short* __restrict__ xb) {
  int s = blockIdx.x * 2 + (threadIdx.x >> 7);
  if (s >= ctr[1]) return;
  int d = threadIdx.x & 127;
  xb[(size_t)s * 128 + d] = f2bf(x[(size_t)sNodes[s] * D_IN + d]);
}

// Pack W=[W1;root1] (1152x128) into MFMA B-fragment order, bf16:
// frag f=(kt*8+nt)*64+lane holds W[kt*32 + (lane>>4)*8 + j][nt*16 + (lane&15)].
__global__ __launch_bounds__(64) void k_wprep(
    const float* __restrict__ W1, const float* __restrict__ root1,
    unsigned short* __restrict__ Wt) {
  int blk = blockIdx.x;            // 0..287 = kt*8+nt
  int kt = blk >> 3, nt = blk & 7;
  int lane = threadIdx.x;
  int k0 = kt * 32 + (lane >> 4) * 8;
  int n = nt * 16 + (lane & 15);
  v8s frag;
#pragma unroll
  for (int j = 0; j < 8; j++) {
    int kg = k0 + j;
    float v = (kg < 1024) ? W1[(size_t)kg * D_HID + n]
                          : root1[(size_t)(kg - 1024) * D_HID + n];
    frag[j] = (short)f2bf(v);
  }
  ((v8s*)Wt)[blk * 64 + lane] = frag;
}

// Layer-1 GEMM via bf16 MFMA 16x16x32. A=[agg1b means | xb] (M x 1152),
// B=Wt (1152 x 128). Wave computes a 16x128 strip; frags load straight from
// global (coalesced short8), no LDS. h = relu(A@W + b1), fp32.
__global__ __launch_bounds__(256) void k_gemm1(
    const unsigned short* __restrict__ agg1b, const unsigned short* __restrict__ xb,
    const unsigned short* __restrict__ Wt, const float* __restrict__ b1,
    const int* __restrict__ ctr, float* __restrict__ h) {
  int sCount = ctr[1];
  int wave = threadIdx.x >> 6, lane = threadIdx.x & 63;
  int s0 = blockIdx.x * 64 + wave * 16;
  if (s0 >= sCount) return;
  int quad = lane >> 4, mn = lane & 15;
  int srow = s0 + mn;                        // A row this lane supplies
  v4f acc[8];
#pragma unroll
  for (int i = 0; i < 8; i++) acc[i] = (v4f){0.f, 0.f, 0.f, 0.f};
  const v8s* WtF = (const v8s*)Wt;
  for (int kt = 0; kt < 36; kt++) {
    const unsigned short* aptr;
    if (kt < 32) {                           // mean-agg part: k = r*128 + d
      int r = kt >> 2;
      int d0 = (kt & 3) * 32 + quad * 8;
      aptr = agg1b + ((size_t)(r * CAP_S + srow) * 128 + d0);
    } else {                                 // root part: k = 1024 + d
      int d0 = (kt - 32) * 32 + quad * 8;
      aptr = xb + ((size_t)srow * 128 + d0);
    }
    v8s afrag = *(const v8s*)aptr;
    const v8s* wrow = WtF + (size_t)(kt * 8) * 64 + lane;
#pragma unroll
    for (int nt = 0; nt < 8; nt++) {
      v8s bfrag = wrow[nt * 64];
      acc[nt] = __builtin_amdgcn_mfma_f32_16x16x32_bf16(afrag, bfrag, acc[nt], 0, 0, 0);
    }
  }
#pragma unroll
  for (int nt = 0; nt < 8; nt++) {
    int col = nt * 16 + mn;
    float bv = b1[col];
#pragma unroll
    for (int reg = 0; reg < 4; reg++) {
      int s = s0 + quad * 4 + reg;           // C/D: row=(lane>>4)*4+reg, col=lane&15
      if (s < sCount)
        h[(size_t)s * D_HID + col] = fmaxf(acc[nt][reg] + bv, 0.0f);
    }
  }
}

// Layer-2 scatter: re-scan edges; pooled-dst hits (~8k) scatter h rows into
// agg2 with coalesced wave atomics (tiny traffic; atomics fine here).
__global__ __launch_bounds__(256) void k_scatter2(
    const int* __restrict__ EI, const int* __restrict__ ET,
    const unsigned* __restrict__ pBit, const int* __restrict__ pId,
    const int* __restrict__ sId, const float* __restrict__ h,
    float* __restrict__ agg2, float* __restrict__ cnt2) {
  __shared__ int2 hits[CHUNK];
  __shared__ int lcnt;
  int tid = threadIdx.x;
  int nChunks = (N_EDGES + CHUNK - 1) / CHUNK;
  for (int c = blockIdx.x; c < nChunks; c += gridDim.x) {
    if (tid == 0) lcnt = 0;
    __syncthreads();
    int e0 = c * CHUNK + tid * 4;
    if (e0 + 3 < N_EDGES) {
      int4 d4 = *(const int4*)(EI + N_EDGES + e0);
      int d[4] = {d4.x, d4.y, d4.z, d4.w};
#pragma unroll
      for (int i = 0; i < 4; i++) {
        int dst = d[i];
        if ((pBit[dst >> 5] >> (dst & 31)) & 1u) {
          int e = e0 + i;
          int code = ET[e] * N_POOL + (pId[dst] - 1);
          int sl = sId[EI[e]] - 1;
          atomAddF(&cnt2[code], 1.0f);
          int p = atomicAdd(&lcnt, 1);
          hits[p] = make_int2(sl, code);
        }
      }
    } else {
      for (int i = 0; i < 4; i++) {
        int e = e0 + i;
        if (e < N_EDGES) {
          int dst = EI[N_EDGES + e];
          if ((pBit[dst >> 5] >> (dst & 31)) & 1u) {
            int code = ET[e] * N_POOL + (pId[dst] - 1);
            int sl = sId[EI[e]] - 1;
            atomAddF(&cnt2[code], 1.0f);
            int p = atomicAdd(&lcnt, 1);
            hits[p] = make_int2(sl, code);
          }
        }
      }
    }
    __syncthreads();
    int nh = lcnt;
    int wid = tid >> 6, lane = tid & 63;
    for (int i = wid; i < nh; i += 4) {
      int2 sc = hits[i];
      const float* hr = h + (size_t)sc.x * D_HID;
      float* ar = agg2 + (size_t)sc.y * D_HID;
      atomAddF(&ar[lane],      hr[lane]);
      atomAddF(&ar[lane + 64], hr[lane + 64]);
    }
    __syncthreads();
  }
}

// Layer-2 GEMM per pooled node, 4-way K-split + LDS reduce.
__global__ __launch_bounds__(256) void k_gemm2(
    const float* __restrict__ W2, const float* __restrict__ root2,
    const float* __restrict__ b2, const float* __restrict__ agg2,
    const float* __restrict__ cnt2, const int* __restrict__ pNodes,
    const int* __restrict__ sId, const int* __restrict__ ctr,
    const float* __restrict__ h, float* __restrict__ emb) {
  __shared__ float a[N_REL * D_HID + D_HID];  // 1152
  __shared__ float inv[N_REL];
  __shared__ float partial[256];
  int pl = blockIdx.x;
  if (pl >= ctr[0]) return;
  int tid = threadIdx.x;
  if (tid < N_REL) inv[tid] = 1.0f / fmaxf(cnt2[tid * N_POOL + pl], 1.0f);
  __syncthreads();
  for (int k = tid; k < 1024; k += 256) {
    int r = k >> 7, d = k & 127;
    a[k] = agg2[(size_t)(r * N_POOL + pl) * D_HID + d] * inv[r];
  }
  if (tid < 128) {
    int slp = sId[pNodes[pl]] - 1;
    a[1024 + tid] = h[(size_t)slp * D_HID + tid];
  }
  __syncthreads();
  int ksl = tid >> 6, c = tid & 63;
  int lo = ksl * 288, hi = lo + 288;
  float acc = 0.0f;
  int hiW = (hi < 1024) ? hi : 1024;
#pragma unroll 4
  for (int k = lo; k < hiW; k++) acc += a[k] * W2[(size_t)k * D_OUT + c];
  int loR = (lo > 1024) ? lo : 1024;
#pragma unroll 4
  for (int k = loR; k < hi; k++) acc += a[k] * root2[(size_t)(k - 1024) * D_OUT + c];
  partial[tid] = acc;
  __syncthreads();
  if (tid < 64) {
    float r = partial[tid] + partial[tid + 64] + partial[tid + 128] + partial[tid + 192];
    emb[(size_t)pl * D_OUT + tid] = r + b2[tid];
  }
}

// Weighted pooling.
__global__ __launch_bounds__(256) void k_pool(
    const float* __restrict__ x, const int* __restrict__ pool,
    const int* __restrict__ pId, const float* __restrict__ emb,
    float* __restrict__ out) {
  __shared__ float ew[N_POOL];
  __shared__ int pls[N_POOL];
  int tid = threadIdx.x;
  int node = pool[tid];
  const float* xr = x + (size_t)node * D_IN;
  ew[tid] = 4.0f * xr[0] + 1.0f * xr[1] + 2.0f * xr[2];
  pls[tid] = pId[node] - 1;
  __syncthreads();
  if (tid < D_OUT) {
    float sw = 0.0f;
    for (int j = 0; j < N_POOL; j++) sw += ew[j];
    float acc = 0.0f;
    for (int j = 0; j < N_POOL; j++) acc += ew[j] * emb[(size_t)pls[j] * D_OUT + tid];
    out[tid] = acc / (sw + 1e-9f);
  }
}

extern "C" void kernel_launch(void* const* d_in, const int* in_sizes, int n_in,
                              void* d_out, int out_size, void* d_ws, size_t ws_size,
                              hipStream_t stream) {
  const float* x     = (const float*)d_in[0];
  const int*   EI    = (const int*)  d_in[1];
  const int*   ET    = (const int*)  d_in[2];
  const int*   pool  = (const int*)  d_in[3];
  const float* W1    = (const float*)d_in[4];
  const float* root1 = (const float*)d_in[5];
  const float* b1    = (const float*)d_in[6];
  const float* W2    = (const float*)d_in[7];
  const float* root2 = (const float*)d_in[8];
  const float* b2    = (const float*)d_in[9];
  float* out = (float*)d_out;

  float* ws = (float*)d_ws;
  int*      cntArr  = (int*)(ws + OFF_CNTA);
  int*      fillCtr = (int*)(ws + OFF_FILLC);
  float*    agg2    = ws + OFF_AGG2;
  float*    cnt2    = ws + OFF_CNT2;
  unsigned* pBit    = (unsigned*)(ws + OFF_PBIT);
  unsigned* sBit    = (unsigned*)(ws + OFF_SBIT);
  int*      ctr     = (int*)(ws + OFF_CTR);
  int*      ptrA    = (int*)(ws + OFF_PTRA);
  int*      bsum    = (int*)(ws + OFF_BSUM);
  int*      boff    = (int*)(ws + OFF_BOFF);
  int*      pId     = (int*)(ws + OFF_PID);
  int*      sId     = (int*)(ws + OFF_SID);
  int*      pNodes  = (int*)(ws + OFF_PNODES);
  int*      sNodes  = (int*)(ws + OFF_SNODES);
  int*      srcSlot = (int*)(ws + OFF_SRCSLOT);
  unsigned short* agg1b = (unsigned short*)(ws + OFF_AGG1B);
  unsigned short* xb    = (unsigned short*)(ws + OFF_XB);
  unsigned short* Wt    = (unsigned short*)(ws + OFF_WT);
  float*    h       = ws + OFF_H;
  float*    emb     = ws + OFF_EMB;

  k_zero<<<512, 256, 0, stream>>>((float4*)ws, (long)(ZERO_ELEMS / 4));
  k_mark_pooled<<<1, 256, 0, stream>>>(pool, pBit, pId, pNodes, sBit, ctr);
  k_pass1<<<(N_EDGES / 4 + 255) / 256, 256, 0, stream>>>(EI, pBit, sBit);
  k_compactS<<<(N_NODES + 255) / 256, 256, 0, stream>>>(sBit, sId, sNodes, ctr);
  k_count<<<(N_EDGES / 4 + 255) / 256, 256, 0, stream>>>(EI, ET, sBit, sId, cntArr);
  k_scanA<<<NSEG / 1024, 256, 0, stream>>>(cntArr, ptrA, bsum);
  k_scanB<<<1, 128, 0, stream>>>(bsum, boff);
  k_scanC<<<NSEG / 256, 256, 0, stream>>>(ptrA, boff);
  k_fill<<<(N_EDGES / 4 + 255) / 256, 256, 0, stream>>>(EI, ET, sBit, sId, ptrA, fillCtr, srcSlot);
  k_wprep<<<288, 64, 0, stream>>>(W1, root1, Wt);
  k_xconvert<<<CAP_S / 2, 256, 0, stream>>>(x, sNodes, ctr, xb);
  k_gather<<<NSEG / 4, 256, 0, stream>>>(ptrA, cntArr, srcSlot, x, ctr, agg1b);
  k_gemm1<<<CAP_S / 64, 256, 0, stream>>>(agg1b, xb, Wt, b1, ctr, h);
  k_scatter2<<<1024, 256, 0, stream>>>(EI, ET, pBit, pId, sId, h, agg2, cnt2);
  k_gemm2<<<N_POOL, 256, 0, stream>>>(W2, root2, b2, agg2, cnt2, pNodes, sId, ctr, h, emb);
  k_pool<<<1, 256, 0, stream>>>(x, pool, pId, emb, out);
}

// Round 5
// 250.551 us; speedup vs baseline: 3.4012x; 1.1519x over previous
//
#include <hip/hip_runtime.h>

// Problem constants (fixed by the reference setup_inputs).
#define N_NODES 50000
#define N_EDGES 1600000
#define N_REL   8
#define D_IN    128
#define D_HID   128
#define D_OUT   64
#define N_POOL  256

// Sparse dependency cone capacities (fixed seed; expected |S|~7700,
// edges-into-S ~250k; CAP_S has >1.5x margin, writes clamped).
#define CAP_S   12288
#define CAP_E1  393216
#define NSEG    (N_REL * CAP_S)     // 98304 segments (r, s-local)
#define CHUNK   1024

typedef short v8s __attribute__((ext_vector_type(8)));
typedef float v4f __attribute__((ext_vector_type(4)));

// ---- workspace layout (element offsets, 4B units) ----
// Zero-initialized region:
constexpr size_t OFF_CNTA   = 0;                       // NSEG int
constexpr size_t OFF_FILLC  = OFF_CNTA + NSEG;         // NSEG int
constexpr size_t OFF_AGG2   = OFF_FILLC + NSEG;        // 8*256*128 fp32
constexpr size_t OFF_CNT2   = OFF_AGG2 + (size_t)N_REL * N_POOL * D_HID;
constexpr size_t OFF_PBIT   = OFF_CNT2 + (size_t)N_REL * N_POOL;
constexpr size_t OFF_SBIT   = OFF_PBIT + 2048;
constexpr size_t OFF_CTR    = OFF_SBIT + 2048;         // 8 int
constexpr size_t ZERO_ELEMS = OFF_CTR + 8;
// Write-before-read region:
constexpr size_t OFF_PTRA   = ZERO_ELEMS;              // NSEG int
constexpr size_t OFF_BSUM   = OFF_PTRA + NSEG;         // 128 int
constexpr size_t OFF_BOFF   = OFF_BSUM + 128;          // 128 int
constexpr size_t OFF_PID    = OFF_BOFF + 128;          // N_NODES int
constexpr size_t OFF_SID    = OFF_PID + N_NODES;       // N_NODES int
constexpr size_t OFF_PNODES = OFF_SID + N_NODES;       // 256 int
constexpr size_t OFF_SNODES = OFF_PNODES + N_POOL;     // CAP_S int
constexpr size_t OFF_SRCSLOT= OFF_SNODES + CAP_S;      // CAP_E1 int
constexpr size_t OFF_AGG1B  = OFF_SRCSLOT + CAP_E1;    // NSEG*128 bf16
constexpr size_t OFF_XB     = OFF_AGG1B + (size_t)NSEG * 128 / 2;   // CAP_S*128 bf16
constexpr size_t OFF_WT     = OFF_XB + (size_t)CAP_S * 128 / 2;     // 1152*128 bf16
constexpr size_t OFF_H      = OFF_WT + (size_t)1152 * 128 / 2;      // CAP_S*128 fp32
constexpr size_t OFF_EMB    = OFF_H + (size_t)CAP_S * D_HID;        // 256*64 fp32
constexpr size_t TOTAL_ELEMS= OFF_EMB + (size_t)N_POOL * D_OUT;

// counters: [0]=pCount, [1]=sCount

__device__ __forceinline__ void atomAddF(float* p, float v) { unsafeAtomicAdd(p, v); }

__device__ __forceinline__ unsigned short f2bf(float f) {   // RNE fp32 -> bf16
  union { float f; unsigned u; } v; v.f = f;
  unsigned r = v.u + 0x7FFFu + ((v.u >> 16) & 1u);
  return (unsigned short)(r >> 16);
}

__global__ void k_zero(float4* __restrict__ p, long n4) {
  long i = (long)blockIdx.x * blockDim.x + threadIdx.x;
  long stride = (long)gridDim.x * blockDim.x;
  float4 z = {0.f, 0.f, 0.f, 0.f};
  for (; i < n4; i += stride) p[i] = z;
}

// Only set membership bits (compaction happens in k_compactS — no serial chain).
__global__ __launch_bounds__(256) void k_mark_pooled(
    const int* __restrict__ pool, unsigned* pBit, unsigned* sBit) {
  int node = pool[threadIdx.x];
  unsigned bit = 1u << (node & 31);
  atomicOr(&pBit[node >> 5], bit);
  atomicOr(&sBit[node >> 5], bit);
}

// Pass 1: mark sources of pooled-dst edges into sBit (int4-vectorized dst scan).
__global__ __launch_bounds__(256) void k_pass1(
    const int* __restrict__ EI, const unsigned* __restrict__ pBit, unsigned* sBit) {
  int idx = blockIdx.x * 256 + threadIdx.x;
  if (idx >= N_EDGES / 4) return;
  int4 d4 = ((const int4*)(EI + N_EDGES))[idx];
  int d[4] = {d4.x, d4.y, d4.z, d4.w};
#pragma unroll
  for (int i = 0; i < 4; i++) {
    int dst = d[i];
    if ((pBit[dst >> 5] >> (dst & 31)) & 1u) {
      int src = EI[idx * 4 + i];
      atomicOr(&sBit[src >> 5], 1u << (src & 31));
    }
  }
}

// Number S (block-aggregated: one global atomic per 256-node block) and P
// (wave-aggregated; pooled hits are rare).
__global__ __launch_bounds__(256) void k_compactS(
    const unsigned* __restrict__ sBit, const unsigned* __restrict__ pBit,
    int* sId, int* sNodes, int* pId, int* pNodes, int* ctr) {
  __shared__ int wcnt[4];
  __shared__ int sbase;
  int tid = threadIdx.x, wave = tid >> 6, lane = tid & 63;
  int node = blockIdx.x * 256 + tid;
  bool sp = (node < N_NODES) && ((sBit[node >> 5] >> (node & 31)) & 1u);
  unsigned long long m = __ballot(sp);
  if (lane == 0) wcnt[wave] = __popcll(m);
  __syncthreads();
  if (tid == 0) {
    int tot = wcnt[0] + wcnt[1] + wcnt[2] + wcnt[3];
    sbase = tot ? atomicAdd(&ctr[1], tot) : 0;
  }
  __syncthreads();
  if (sp) {
    int off = sbase;
    for (int w2 = 0; w2 < wave; w2++) off += wcnt[w2];
    int id = off + __popcll(m & ((1ull << lane) - 1ull));
    if (id < CAP_S) { sId[node] = id + 1; sNodes[id] = node; }
    else sId[node] = 0;
  }
  bool pp = (node < N_NODES) && ((pBit[node >> 5] >> (node & 31)) & 1u);
  unsigned long long pm = __ballot(pp);
  if (pm) {
    int leader = __ffsll(pm) - 1;
    int base = 0;
    if (lane == leader) base = atomicAdd(&ctr[0], __popcll(pm));
    base = __shfl(base, leader);
    if (pp) {
      int id = base + __popcll(pm & ((1ull << lane) - 1ull));
      pId[node] = id + 1;
      pNodes[id] = node;
    }
  }
}

// Count edges per (rel, s-local) segment.
__global__ __launch_bounds__(256) void k_count(
    const int* __restrict__ EI, const int* __restrict__ ET,
    const unsigned* __restrict__ sBit, const int* __restrict__ sId,
    int* __restrict__ cntArr) {
  int idx = blockIdx.x * 256 + threadIdx.x;
  if (idx >= N_EDGES / 4) return;
  int4 d4 = ((const int4*)(EI + N_EDGES))[idx];
  int4 t4 = ((const int4*)ET)[idx];
  int d[4] = {d4.x, d4.y, d4.z, d4.w};
  int t[4] = {t4.x, t4.y, t4.z, t4.w};
#pragma unroll
  for (int i = 0; i < 4; i++) {
    int dst = d[i];
    if ((sBit[dst >> 5] >> (dst & 31)) & 1u) {
      int sp = sId[dst];
      if (sp > 0) atomicAdd(&cntArr[t[i] * CAP_S + (sp - 1)], 1);
    }
  }
}

// Prefix scan over NSEG counts (3 kernels).
__global__ __launch_bounds__(256) void k_scanA(
    const int* __restrict__ cntArr, int* __restrict__ ptrA, int* __restrict__ bsum) {
  __shared__ int sd[256];
  int t = threadIdx.x;
  int base = blockIdx.x * 1024 + t * 4;
  int4 c4 = ((const int4*)cntArr)[base >> 2];
  int ts = c4.x + c4.y + c4.z + c4.w;
  sd[t] = ts; __syncthreads();
  for (int off = 1; off < 256; off <<= 1) {
    int v = (t >= off) ? sd[t - off] : 0;
    __syncthreads();
    sd[t] += v;
    __syncthreads();
  }
  int excl = sd[t] - ts;
  int4 o; o.x = excl; o.y = excl + c4.x; o.z = o.y + c4.y; o.w = o.z + c4.z;
  ((int4*)ptrA)[base >> 2] = o;
  if (t == 255) bsum[blockIdx.x] = sd[255];
}

__global__ __launch_bounds__(128) void k_scanB(
    const int* __restrict__ bsum, int* __restrict__ boff) {
  __shared__ int sd[128];
  int t = threadIdx.x;
  int v = (t < 96) ? bsum[t] : 0;
  sd[t] = v; __syncthreads();
  for (int off = 1; off < 128; off <<= 1) {
    int u = (t >= off) ? sd[t - off] : 0;
    __syncthreads();
    sd[t] += u;
    __syncthreads();
  }
  if (t < 96) boff[t] = sd[t] - v;
}

__global__ __launch_bounds__(256) void k_scanC(
    int* __restrict__ ptrA, const int* __restrict__ boff) {
  int i = blockIdx.x * 256 + threadIdx.x;
  if (i < NSEG) ptrA[i] += boff[i >> 10];
}

// Fill CSR edge slots.
__global__ __launch_bounds__(256) void k_fill(
    const int* __restrict__ EI, const int* __restrict__ ET,
    const unsigned* __restrict__ sBit, const int* __restrict__ sId,
    const int* __restrict__ ptrA, int* __restrict__ fillCtr,
    int* __restrict__ srcSlot) {
  int idx = blockIdx.x * 256 + threadIdx.x;
  if (idx >= N_EDGES / 4) return;
  int4 d4 = ((const int4*)(EI + N_EDGES))[idx];
  int4 t4 = ((const int4*)ET)[idx];
  int4 s4 = ((const int4*)EI)[idx];
  int d[4] = {d4.x, d4.y, d4.z, d4.w};
  int t[4] = {t4.x, t4.y, t4.z, t4.w};
  int s[4] = {s4.x, s4.y, s4.z, s4.w};
#pragma unroll
  for (int i = 0; i < 4; i++) {
    int dst = d[i];
    if ((sBit[dst >> 5] >> (dst & 31)) & 1u) {
      int sp = sId[dst];
      if (sp > 0) {
        int seg = t[i] * CAP_S + (sp - 1);
        int slot = ptrA[seg] + atomicAdd(&fillCtr[seg], 1);
        if (slot < CAP_E1) srcSlot[slot] = s[i];
      }
    }
  }
}

// Gather-reduce: one wave per segment; float2 loads; write MEAN in bf16.
__global__ __launch_bounds__(256) void k_gather(
    const int* __restrict__ ptrA, const int* __restrict__ cntArr,
    const int* __restrict__ srcSlot, const float* __restrict__ x,
    const int* __restrict__ ctr, unsigned short* __restrict__ agg1b) {
  int w = (blockIdx.x << 2) + (threadIdx.x >> 6);
  if (w % CAP_S >= ctr[1]) return;
  int lane = threadIdx.x & 63;
  int begin = ptrA[w];
  int cnt = cntArr[w];
  float a0 = 0.f, a1 = 0.f;
  const float2* x2 = (const float2*)x;
  for (int i = 0; i < cnt; i++) {
    int src = srcSlot[begin + i];
    float2 v = x2[(size_t)src * 64 + lane];
    a0 += v.x; a1 += v.y;
  }
  float inv = 1.0f / fmaxf((float)cnt, 1.0f);
  ushort2 o = { f2bf(a0 * inv), f2bf(a1 * inv) };
  ((ushort2*)agg1b)[(size_t)w * 64 + lane] = o;
}

// Convert x rows of S-nodes to bf16.
__global__ __launch_bounds__(256) void k_xconvert(
    const float* __restrict__ x, const int* __restrict__ sNodes,
    const int* __restrict__ ctr, unsigned short* __restrict__ xb) {
  int s = blockIdx.x * 4 + (threadIdx.x >> 6);
  if (s >= ctr[1]) return;
  int lane = threadIdx.x & 63;
  float2 v = ((const float2*)x)[(size_t)sNodes[s] * 64 + lane];
  ushort2 o = { f2bf(v.x), f2bf(v.y) };
  ((ushort2*)xb)[(size_t)s * 64 + lane] = o;
}

// Pack W=[W1;root1] (1152x128) into MFMA B-fragment order, bf16.
__global__ __launch_bounds__(64) void k_wprep(
    const float* __restrict__ W1, const float* __restrict__ root1,
    unsigned short* __restrict__ Wt) {
  int blk = blockIdx.x;            // 0..287 = kt*8+nt
  int kt = blk >> 3, nt = blk & 7;
  int lane = threadIdx.x;
  int k0 = kt * 32 + (lane >> 4) * 8;
  int n = nt * 16 + (lane & 15);
  v8s frag;
#pragma unroll
  for (int j = 0; j < 8; j++) {
    int kg = k0 + j;
    float v = (kg < 1024) ? W1[(size_t)kg * D_HID + n]
                          : root1[(size_t)(kg - 1024) * D_HID + n];
    frag[j] = (short)f2bf(v);
  }
  ((v8s*)Wt)[blk * 64 + lane] = frag;
}

// Layer-1 GEMM via bf16 MFMA 16x16x32, K-split x4 + N-split x2 for occupancy.
// Block = 16 rows x 64 cols; wave w handles K-steps [w*9, w*9+9); LDS reduce.
__global__ __launch_bounds__(256) void k_gemm1(
    const unsigned short* __restrict__ agg1b, const unsigned short* __restrict__ xb,
    const unsigned short* __restrict__ Wt, const float* __restrict__ b1,
    const int* __restrict__ ctr, float* __restrict__ h) {
  __shared__ float red[4][16][64];           // [wave][nt*4+reg][lane] = 16 KB
  int sCount = ctr[1];
  int s0 = blockIdx.x * 16;
  if (s0 >= sCount) return;
  int colTile = blockIdx.y;                  // 0..1
  int wave = threadIdx.x >> 6, lane = threadIdx.x & 63;
  int quad = lane >> 4, mn = lane & 15;
  int srow = s0 + mn;
  v4f acc[4];
#pragma unroll
  for (int i = 0; i < 4; i++) acc[i] = (v4f){0.f, 0.f, 0.f, 0.f};
  const v8s* WtF = (const v8s*)Wt;
  int kt0 = wave * 9, kt1 = kt0 + 9;
  for (int kt = kt0; kt < kt1; kt++) {
    const unsigned short* aptr;
    if (kt < 32) {                           // mean-agg part: k = r*128 + d
      int r = kt >> 2;
      int d0 = (kt & 3) * 32 + quad * 8;
      aptr = agg1b + ((size_t)(r * CAP_S + srow) * 128 + d0);
    } else {                                 // root part
      int d0 = (kt - 32) * 32 + quad * 8;
      aptr = xb + ((size_t)srow * 128 + d0);
    }
    v8s afrag = *(const v8s*)aptr;
    const v8s* wrow = WtF + (size_t)(kt * 8 + colTile * 4) * 64 + lane;
#pragma unroll
    for (int nt = 0; nt < 4; nt++) {
      v8s bfrag = wrow[nt * 64];
      acc[nt] = __builtin_amdgcn_mfma_f32_16x16x32_bf16(afrag, bfrag, acc[nt], 0, 0, 0);
    }
  }
#pragma unroll
  for (int nt = 0; nt < 4; nt++)
#pragma unroll
    for (int reg = 0; reg < 4; reg++)
      red[wave][nt * 4 + reg][lane] = acc[nt][reg];
  __syncthreads();
  // Reduce: wave id = nt2, lanes sweep the 64-lane axis (conflict-free).
  int nt2 = threadIdx.x >> 6;
  int lane2 = threadIdx.x & 63;
  int quad2 = lane2 >> 4, mn2 = lane2 & 15;
#pragma unroll
  for (int reg = 0; reg < 4; reg++) {
    int idx = nt2 * 4 + reg;
    float v = red[0][idx][lane2] + red[1][idx][lane2]
            + red[2][idx][lane2] + red[3][idx][lane2];
    int s = s0 + quad2 * 4 + reg;
    int col = colTile * 64 + nt2 * 16 + mn2;
    if (s < sCount)
      h[(size_t)s * D_HID + col] = fmaxf(v + b1[col], 0.0f);
  }
}

// Layer-2 scatter: re-scan edges; pooled-dst hits (~8k) scatter h rows.
__global__ __launch_bounds__(256) void k_scatter2(
    const int* __restrict__ EI, const int* __restrict__ ET,
    const unsigned* __restrict__ pBit, const int* __restrict__ pId,
    const int* __restrict__ sId, const float* __restrict__ h,
    float* __restrict__ agg2, float* __restrict__ cnt2) {
  __shared__ int2 hits[CHUNK];
  __shared__ int lcnt;
  int tid = threadIdx.x;
  int nChunks = (N_EDGES + CHUNK - 1) / CHUNK;
  for (int c = blockIdx.x; c < nChunks; c += gridDim.x) {
    if (tid == 0) lcnt = 0;
    __syncthreads();
    int e0 = c * CHUNK + tid * 4;
    if (e0 + 3 < N_EDGES) {
      int4 d4 = *(const int4*)(EI + N_EDGES + e0);
      int d[4] = {d4.x, d4.y, d4.z, d4.w};
#pragma unroll
      for (int i = 0; i < 4; i++) {
        int dst = d[i];
        if ((pBit[dst >> 5] >> (dst & 31)) & 1u) {
          int e = e0 + i;
          int code = ET[e] * N_POOL + (pId[dst] - 1);
          int sl = sId[EI[e]] - 1;
          atomAddF(&cnt2[code], 1.0f);
          int p = atomicAdd(&lcnt, 1);
          hits[p] = make_int2(sl, code);
        }
      }
    }
    __syncthreads();
    int nh = lcnt;
    int wid = tid >> 6, lane = tid & 63;
    for (int i = wid; i < nh; i += 4) {
      int2 sc = hits[i];
      const float* hr = h + (size_t)sc.x * D_HID;
      float* ar = agg2 + (size_t)sc.y * D_HID;
      atomAddF(&ar[lane],      hr[lane]);
      atomAddF(&ar[lane + 64], hr[lane + 64]);
    }
    __syncthreads();
  }
}

// Layer-2 GEMM per pooled node, 4-way K-split + LDS reduce.
__global__ __launch_bounds__(256) void k_gemm2(
    const float* __restrict__ W2, const float* __restrict__ root2,
    const float* __restrict__ b2, const float* __restrict__ agg2,
    const float* __restrict__ cnt2, const int* __restrict__ pNodes,
    const int* __restrict__ sId, const int* __restrict__ ctr,
    const float* __restrict__ h, float* __restrict__ emb) {
  __shared__ float a[N_REL * D_HID + D_HID];  // 1152
  __shared__ float inv[N_REL];
  __shared__ float partial[256];
  int pl = blockIdx.x;
  if (pl >= ctr[0]) return;
  int tid = threadIdx.x;
  if (tid < N_REL) inv[tid] = 1.0f / fmaxf(cnt2[tid * N_POOL + pl], 1.0f);
  __syncthreads();
  for (int k = tid; k < 1024; k += 256) {
    int r = k >> 7, d = k & 127;
    a[k] = agg2[(size_t)(r * N_POOL + pl) * D_HID + d] * inv[r];
  }
  if (tid < 128) {
    int slp = sId[pNodes[pl]] - 1;
    a[1024 + tid] = h[(size_t)slp * D_HID + tid];
  }
  __syncthreads();
  int ksl = tid >> 6, c = tid & 63;
  int lo = ksl * 288, hi = lo + 288;
  float acc = 0.0f;
  int hiW = (hi < 1024) ? hi : 1024;
#pragma unroll 4
  for (int k = lo; k < hiW; k++) acc += a[k] * W2[(size_t)k * D_OUT + c];
  int loR = (lo > 1024) ? lo : 1024;
#pragma unroll 4
  for (int k = loR; k < hi; k++) acc += a[k] * root2[(size_t)(k - 1024) * D_OUT + c];
  partial[tid] = acc;
  __syncthreads();
  if (tid < 64) {
    float r = partial[tid] + partial[tid + 64] + partial[tid + 128] + partial[tid + 192];
    emb[(size_t)pl * D_OUT + tid] = r + b2[tid];
  }
}

// Weighted pooling.
__global__ __launch_bounds__(256) void k_pool(
    const float* __restrict__ x, const int* __restrict__ pool,
    const int* __restrict__ pId, const float* __restrict__ emb,
    float* __restrict__ out) {
  __shared__ float ew[N_POOL];
  __shared__ int pls[N_POOL];
  int tid = threadIdx.x;
  int node = pool[tid];
  const float* xr = x + (size_t)node * D_IN;
  ew[tid] = 4.0f * xr[0] + 1.0f * xr[1] + 2.0f * xr[2];
  pls[tid] = pId[node] - 1;
  __syncthreads();
  if (tid < D_OUT) {
    float sw = 0.0f;
    for (int j = 0; j < N_POOL; j++) sw += ew[j];
    float acc = 0.0f;
    for (int j = 0; j < N_POOL; j++) acc += ew[j] * emb[(size_t)pls[j] * D_OUT + tid];
    out[tid] = acc / (sw + 1e-9f);
  }
}

extern "C" void kernel_launch(void* const* d_in, const int* in_sizes, int n_in,
                              void* d_out, int out_size, void* d_ws, size_t ws_size,
                              hipStream_t stream) {
  const float* x     = (const float*)d_in[0];
  const int*   EI    = (const int*)  d_in[1];
  const int*   ET    = (const int*)  d_in[2];
  const int*   pool  = (const int*)  d_in[3];
  const float* W1    = (const float*)d_in[4];
  const float* root1 = (const float*)d_in[5];
  const float* b1    = (const float*)d_in[6];
  const float* W2    = (const float*)d_in[7];
  const float* root2 = (const float*)d_in[8];
  const float* b2    = (const float*)d_in[9];
  float* out = (float*)d_out;

  float* ws = (float*)d_ws;
  int*      cntArr  = (int*)(ws + OFF_CNTA);
  int*      fillCtr = (int*)(ws + OFF_FILLC);
  float*    agg2    = ws + OFF_AGG2;
  float*    cnt2    = ws + OFF_CNT2;
  unsigned* pBit    = (unsigned*)(ws + OFF_PBIT);
  unsigned* sBit    = (unsigned*)(ws + OFF_SBIT);
  int*      ctr     = (int*)(ws + OFF_CTR);
  int*      ptrA    = (int*)(ws + OFF_PTRA);
  int*      bsum    = (int*)(ws + OFF_BSUM);
  int*      boff    = (int*)(ws + OFF_BOFF);
  int*      pId     = (int*)(ws + OFF_PID);
  int*      sId     = (int*)(ws + OFF_SID);
  int*      pNodes  = (int*)(ws + OFF_PNODES);
  int*      sNodes  = (int*)(ws + OFF_SNODES);
  int*      srcSlot = (int*)(ws + OFF_SRCSLOT);
  unsigned short* agg1b = (unsigned short*)(ws + OFF_AGG1B);
  unsigned short* xb    = (unsigned short*)(ws + OFF_XB);
  unsigned short* Wt    = (unsigned short*)(ws + OFF_WT);
  float*    h       = ws + OFF_H;
  float*    emb     = ws + OFF_EMB;

  k_zero<<<512, 256, 0, stream>>>((float4*)ws, (long)(ZERO_ELEMS / 4));
  k_mark_pooled<<<1, 256, 0, stream>>>(pool, pBit, sBit);
  k_pass1<<<(N_EDGES / 4 + 255) / 256, 256, 0, stream>>>(EI, pBit, sBit);
  k_compactS<<<(N_NODES + 255) / 256, 256, 0, stream>>>(sBit, pBit, sId, sNodes, pId, pNodes, ctr);
  k_count<<<(N_EDGES / 4 + 255) / 256, 256, 0, stream>>>(EI, ET, sBit, sId, cntArr);
  k_scanA<<<NSEG / 1024, 256, 0, stream>>>(cntArr, ptrA, bsum);
  k_scanB<<<1, 128, 0, stream>>>(bsum, boff);
  k_scanC<<<NSEG / 256, 256, 0, stream>>>(ptrA, boff);
  k_fill<<<(N_EDGES / 4 + 255) / 256, 256, 0, stream>>>(EI, ET, sBit, sId, ptrA, fillCtr, srcSlot);
  k_wprep<<<288, 64, 0, stream>>>(W1, root1, Wt);
  k_xconvert<<<CAP_S / 4, 256, 0, stream>>>(x, sNodes, ctr, xb);
  k_gather<<<NSEG / 4, 256, 0, stream>>>(ptrA, cntArr, srcSlot, x, ctr, agg1b);
  k_gemm1<<<dim3(CAP_S / 16, 2), 256, 0, stream>>>(agg1b, xb, Wt, b1, ctr, h);
  k_scatter2<<<1024, 256, 0, stream>>>(EI, ET, pBit, pId, sId, h, agg2, cnt2);
  k_gemm2<<<N_POOL, 256, 0, stream>>>(W2, root2, b2, agg2, cnt2, pNodes, sId, ctr, h, emb);
  k_pool<<<1, 256, 0, stream>>>(x, pool, pId, emb, out);
}

// Round 6
// 235.866 us; speedup vs baseline: 3.6129x; 1.0623x over previous
//
#include <hip/hip_runtime.h>

// Problem constants (fixed by the reference setup_inputs).
#define N_NODES 50000
#define N_EDGES 1600000
#define N_REL   8
#define D_IN    128
#define D_HID   128
#define D_OUT   64
#define N_POOL  256

// Sparse dependency cone capacities (fixed seed; expected |S|~7700,
// edges-into-S ~250k; CAP_S has >1.5x margin, writes clamped).
#define CAP_S   12288
#define CAP_E1  393216
#define NSEG    (N_REL * CAP_S)     // 98304 segments; encoding seg = s*8 + r
#define CHUNK   1024

typedef short v8s __attribute__((ext_vector_type(8)));
typedef float v4f __attribute__((ext_vector_type(4)));

// ---- workspace layout (element offsets, 4B units) ----
// Zeroed by k_zero:
constexpr size_t OFF_CNTA   = 0;                       // NSEG int
constexpr size_t OFF_FILLC  = OFF_CNTA + NSEG;         // NSEG int
constexpr size_t OFF_AGG2   = OFF_FILLC + NSEG;        // 8*256*128 fp32
constexpr size_t OFF_CNT2   = OFF_AGG2 + (size_t)N_REL * N_POOL * D_HID;  // 2048
constexpr size_t ZERO_ELEMS = OFF_CNT2 + 2048;         // 460,800 (div by 4)
// Zeroed inside k_mark (single block):
constexpr size_t OFF_PBIT   = ZERO_ELEMS;              // 2048 u32
constexpr size_t OFF_SBIT   = OFF_PBIT + 2048;         // 2048 u32
constexpr size_t OFF_CTR    = OFF_SBIT + 2048;         // 8 int  [0]=pCount [1]=sCount
// Write-before-read:
constexpr size_t OFF_PTRA   = OFF_CTR + 8;             // NSEG int (16B-aligned)
constexpr size_t OFF_BSUM   = OFF_PTRA + NSEG;         // 128 int
constexpr size_t OFF_PID    = OFF_BSUM + 128;          // N_NODES int
constexpr size_t OFF_SID    = OFF_PID + N_NODES;       // N_NODES int
constexpr size_t OFF_PNODES = OFF_SID + N_NODES;       // 256 int
constexpr size_t OFF_SNODES = OFF_PNODES + N_POOL;     // CAP_S int
constexpr size_t OFF_SRCSLOT= OFF_SNODES + CAP_S;      // CAP_E1 int
constexpr size_t OFF_AGG1B  = OFF_SRCSLOT + CAP_E1;    // NSEG*64 u32 (bf16 pairs)
constexpr size_t OFF_XALL   = OFF_AGG1B + (size_t)NSEG * 64;      // N_NODES*64 u32
constexpr size_t OFF_WT     = OFF_XALL + (size_t)N_NODES * 64;    // 1152*128 bf16
constexpr size_t OFF_H      = OFF_WT + (size_t)1152 * 128 / 2;    // CAP_S*128 fp32
constexpr size_t OFF_EMB    = OFF_H + (size_t)CAP_S * D_HID;      // 256*64 fp32
constexpr size_t TOTAL_ELEMS= OFF_EMB + (size_t)N_POOL * D_OUT;   // ~49 MB

__device__ __forceinline__ void atomAddF(float* p, float v) { unsafeAtomicAdd(p, v); }

__device__ __forceinline__ unsigned short f2bf(float f) {   // RNE fp32 -> bf16
  union { float f; unsigned u; } v; v.f = f;
  unsigned r = v.u + 0x7FFFu + ((v.u >> 16) & 1u);
  return (unsigned short)(r >> 16);
}
__device__ __forceinline__ float bfLo(unsigned v) { return __uint_as_float(v << 16); }
__device__ __forceinline__ float bfHi(unsigned v) { return __uint_as_float(v & 0xFFFF0000u); }

__global__ void k_zero(float4* __restrict__ p, long n4) {
  long i = (long)blockIdx.x * blockDim.x + threadIdx.x;
  long stride = (long)gridDim.x * blockDim.x;
  float4 z = {0.f, 0.f, 0.f, 0.f};
  for (; i < n4; i += stride) p[i] = z;
}

// Single block: zero bitmaps+ctr itself, then set pooled bits.
__global__ __launch_bounds__(256) void k_mark(
    const int* __restrict__ pool, unsigned* pBit, unsigned* sBit, int* ctr) {
  int tid = threadIdx.x;
  for (int i = tid; i < 2048; i += 256) { pBit[i] = 0u; sBit[i] = 0u; }
  if (tid < 8) ctr[tid] = 0;
  __syncthreads();
  int node = pool[tid];
  unsigned bit = 1u << (node & 31);
  atomicOr(&pBit[node >> 5], bit);
  atomicOr(&sBit[node >> 5], bit);
}

// Pass 1: mark sources of pooled-dst edges into sBit.
__global__ __launch_bounds__(256) void k_pass1(
    const int* __restrict__ EI, const unsigned* __restrict__ pBit, unsigned* sBit) {
  int idx = blockIdx.x * 256 + threadIdx.x;
  if (idx >= N_EDGES / 4) return;
  int4 d4 = ((const int4*)(EI + N_EDGES))[idx];
  int d[4] = {d4.x, d4.y, d4.z, d4.w};
#pragma unroll
  for (int i = 0; i < 4; i++) {
    int dst = d[i];
    if ((pBit[dst >> 5] >> (dst & 31)) & 1u) {
      int src = EI[idx * 4 + i];
      atomicOr(&sBit[src >> 5], 1u << (src & 31));
    }
  }
}

// Number S (block-aggregated atomic) and P (wave-aggregated).
__global__ __launch_bounds__(256) void k_compactS(
    const unsigned* __restrict__ sBit, const unsigned* __restrict__ pBit,
    int* sId, int* sNodes, int* pId, int* pNodes, int* ctr) {
  __shared__ int wcnt[4];
  __shared__ int sbase;
  int tid = threadIdx.x, wave = tid >> 6, lane = tid & 63;
  int node = blockIdx.x * 256 + tid;
  bool sp = (node < N_NODES) && ((sBit[node >> 5] >> (node & 31)) & 1u);
  unsigned long long m = __ballot(sp);
  if (lane == 0) wcnt[wave] = __popcll(m);
  __syncthreads();
  if (tid == 0) {
    int tot = wcnt[0] + wcnt[1] + wcnt[2] + wcnt[3];
    sbase = tot ? atomicAdd(&ctr[1], tot) : 0;
  }
  __syncthreads();
  if (sp) {
    int off = sbase;
    for (int w2 = 0; w2 < wave; w2++) off += wcnt[w2];
    int id = off + __popcll(m & ((1ull << lane) - 1ull));
    if (id < CAP_S) { sId[node] = id + 1; sNodes[id] = node; }
    else sId[node] = 0;
  }
  bool pp = (node < N_NODES) && ((pBit[node >> 5] >> (node & 31)) & 1u);
  unsigned long long pm = __ballot(pp);
  if (pm) {
    int leader = __ffsll(pm) - 1;
    int base = 0;
    if (lane == leader) base = atomicAdd(&ctr[0], __popcll(pm));
    base = __shfl(base, leader);
    if (pp) {
      int id = base + __popcll(pm & ((1ull << lane) - 1ull));
      pId[node] = id + 1;
      pNodes[id] = node;
    }
  }
}

// Count edges per segment (seg = s*8 + r).
__global__ __launch_bounds__(256) void k_count(
    const int* __restrict__ EI, const int* __restrict__ ET,
    const unsigned* __restrict__ sBit, const int* __restrict__ sId,
    int* __restrict__ cntArr) {
  int idx = blockIdx.x * 256 + threadIdx.x;
  if (idx >= N_EDGES / 4) return;
  int4 d4 = ((const int4*)(EI + N_EDGES))[idx];
  int4 t4 = ((const int4*)ET)[idx];
  int d[4] = {d4.x, d4.y, d4.z, d4.w};
  int t[4] = {t4.x, t4.y, t4.z, t4.w};
#pragma unroll
  for (int i = 0; i < 4; i++) {
    int dst = d[i];
    if ((sBit[dst >> 5] >> (dst & 31)) & 1u) {
      int sp = sId[dst];
      if (sp > 0) atomicAdd(&cntArr[((sp - 1) << 3) + t[i]], 1);
    }
  }
}

// Prefix scan over NSEG counts: A (per-1024 block scan) + BC (fused).
__global__ __launch_bounds__(256) void k_scanA(
    const int* __restrict__ cntArr, int* __restrict__ ptrA, int* __restrict__ bsum) {
  __shared__ int sd[256];
  int t = threadIdx.x;
  int base = blockIdx.x * 1024 + t * 4;
  int4 c4 = ((const int4*)cntArr)[base >> 2];
  int ts = c4.x + c4.y + c4.z + c4.w;
  sd[t] = ts; __syncthreads();
  for (int off = 1; off < 256; off <<= 1) {
    int v = (t >= off) ? sd[t - off] : 0;
    __syncthreads();
    sd[t] += v;
    __syncthreads();
  }
  int excl = sd[t] - ts;
  int4 o; o.x = excl; o.y = excl + c4.x; o.z = o.y + c4.y; o.w = o.z + c4.z;
  ((int4*)ptrA)[base >> 2] = o;
  if (t == 255) bsum[blockIdx.x] = sd[255];
}

// Fused scanB+scanC: every block redundantly scans the 96 block sums in LDS,
// then adds the exclusive block offset to its 256 ptrA entries.
__global__ __launch_bounds__(256) void k_scanBC(
    int* __restrict__ ptrA, const int* __restrict__ bsum) {
  __shared__ int sd[128];
  int t = threadIdx.x;
  if (t < 128) sd[t] = (t < 96) ? bsum[t] : 0;
  __syncthreads();
  for (int off = 1; off < 128; off <<= 1) {
    int v = (t < 128 && t >= off) ? sd[t - off] : 0;
    __syncthreads();
    if (t < 128) sd[t] += v;
    __syncthreads();
  }
  int i = blockIdx.x * 256 + t;
  int blk = i >> 10;
  int add = (blk == 0) ? 0 : sd[blk - 1];
  if (i < NSEG) ptrA[i] += add;
}

// Fill CSR edge slots.
__global__ __launch_bounds__(256) void k_fill(
    const int* __restrict__ EI, const int* __restrict__ ET,
    const unsigned* __restrict__ sBit, const int* __restrict__ sId,
    const int* __restrict__ ptrA, int* __restrict__ fillCtr,
    int* __restrict__ srcSlot) {
  int idx = blockIdx.x * 256 + threadIdx.x;
  if (idx >= N_EDGES / 4) return;
  int4 d4 = ((const int4*)(EI + N_EDGES))[idx];
  int4 t4 = ((const int4*)ET)[idx];
  int4 s4 = ((const int4*)EI)[idx];
  int d[4] = {d4.x, d4.y, d4.z, d4.w};
  int t[4] = {t4.x, t4.y, t4.z, t4.w};
  int s[4] = {s4.x, s4.y, s4.z, s4.w};
#pragma unroll
  for (int i = 0; i < 4; i++) {
    int dst = d[i];
    if ((sBit[dst >> 5] >> (dst & 31)) & 1u) {
      int sp = sId[dst];
      if (sp > 0) {
        int seg = ((sp - 1) << 3) + t[i];
        int slot = ptrA[seg] + atomicAdd(&fillCtr[seg], 1);
        if (slot < CAP_E1) srcSlot[slot] = s[i];
      }
    }
  }
}

// Prep: pack W=[W1;root1] into MFMA B-frag order (blocks 0..287) and convert
// all of x to bf16 (remaining blocks, 4 rows each).
__global__ __launch_bounds__(256) void k_prep(
    const float* __restrict__ W1, const float* __restrict__ root1,
    unsigned short* __restrict__ Wt,
    const float* __restrict__ x, unsigned* __restrict__ xall) {
  int b = blockIdx.x;
  if (b < 288) {
    int lane = threadIdx.x;
    if (lane >= 64) return;
    int kt = b >> 3, nt = b & 7;
    int k0 = kt * 32 + (lane >> 4) * 8;
    int n = nt * 16 + (lane & 15);
    v8s frag;
#pragma unroll
    for (int j = 0; j < 8; j++) {
      int kg = k0 + j;
      float v = (kg < 1024) ? W1[(size_t)kg * D_HID + n]
                            : root1[(size_t)(kg - 1024) * D_HID + n];
      frag[j] = (short)f2bf(v);
    }
    ((v8s*)Wt)[b * 64 + lane] = frag;
  } else {
    int row = (b - 288) * 4 + (threadIdx.x >> 6);
    if (row >= N_NODES) return;
    int lane = threadIdx.x & 63;
    float2 v = ((const float2*)x)[(size_t)row * 64 + lane];
    xall[(size_t)row * 64 + lane] = ((unsigned)f2bf(v.y) << 16) | f2bf(v.x);
  }
}

// Gather-reduce: one wave per segment; bf16 row gathers, 4 in flight; write
// MEAN as packed bf16. Active segments contiguous in [0, 8*sCount).
__global__ __launch_bounds__(256) void k_gather(
    const int* __restrict__ ptrA, const int* __restrict__ cntArr,
    const int* __restrict__ srcSlot, const unsigned* __restrict__ xall,
    const int* __restrict__ ctr, unsigned* __restrict__ agg1b) {
  int w = (blockIdx.x << 2) + (threadIdx.x >> 6);
  if (w >= (ctr[1] << 3)) return;
  int lane = threadIdx.x & 63;
  int begin = ptrA[w];
  int cnt = cntArr[w];
  float a0 = 0.f, a1 = 0.f;
  int i = 0;
  for (; i + 4 <= cnt; i += 4) {
    int s0 = srcSlot[begin + i + 0];
    int s1 = srcSlot[begin + i + 1];
    int s2 = srcSlot[begin + i + 2];
    int s3 = srcSlot[begin + i + 3];
    unsigned v0 = xall[(size_t)s0 * 64 + lane];
    unsigned v1 = xall[(size_t)s1 * 64 + lane];
    unsigned v2 = xall[(size_t)s2 * 64 + lane];
    unsigned v3 = xall[(size_t)s3 * 64 + lane];
    a0 += (bfLo(v0) + bfLo(v1)) + (bfLo(v2) + bfLo(v3));
    a1 += (bfHi(v0) + bfHi(v1)) + (bfHi(v2) + bfHi(v3));
  }
  for (; i < cnt; i++) {
    unsigned v = xall[(size_t)srcSlot[begin + i] * 64 + lane];
    a0 += bfLo(v);
    a1 += bfHi(v);
  }
  float inv = 1.0f / fmaxf((float)cnt, 1.0f);
  agg1b[(size_t)w * 64 + lane] = ((unsigned)f2bf(a1 * inv) << 16) | f2bf(a0 * inv);
}

// Layer-1 GEMM via bf16 MFMA 16x16x32, K-split x4 + N-split x2.
// A row srow: [means(seg=srow*8+r) | xall[sNodes[srow]]] (1152), B = Wt.
__global__ __launch_bounds__(256) void k_gemm1(
    const unsigned short* __restrict__ agg1b, const unsigned short* __restrict__ xall,
    const unsigned short* __restrict__ Wt, const float* __restrict__ b1,
    const int* __restrict__ sNodes, const int* __restrict__ ctr,
    float* __restrict__ h) {
  __shared__ float red[4][16][64];           // 16 KB
  int sCount = ctr[1];
  int s0 = blockIdx.x * 16;
  if (s0 >= sCount) return;
  int colTile = blockIdx.y;                  // 0..1
  int wave = threadIdx.x >> 6, lane = threadIdx.x & 63;
  int quad = lane >> 4, mn = lane & 15;
  int srow = s0 + mn;
  int g = (srow < sCount) ? sNodes[srow] : 0;
  v4f acc[4];
#pragma unroll
  for (int i = 0; i < 4; i++) acc[i] = (v4f){0.f, 0.f, 0.f, 0.f};
  const v8s* WtF = (const v8s*)Wt;
  int kt0 = wave * 9, kt1 = kt0 + 9;
  for (int kt = kt0; kt < kt1; kt++) {
    const unsigned short* aptr;
    if (kt < 32) {                           // mean part: k = r*128 + d
      int r = kt >> 2;
      int d0 = (kt & 3) * 32 + quad * 8;
      aptr = agg1b + ((size_t)((srow << 3) + r) * 128 + d0);
    } else {                                 // root part from xall
      int d0 = (kt - 32) * 32 + quad * 8;
      aptr = xall + ((size_t)g * 128 + d0);
    }
    v8s afrag = *(const v8s*)aptr;
    const v8s* wrow = WtF + (size_t)(kt * 8 + colTile * 4) * 64 + lane;
#pragma unroll
    for (int nt = 0; nt < 4; nt++) {
      v8s bfrag = wrow[nt * 64];
      acc[nt] = __builtin_amdgcn_mfma_f32_16x16x32_bf16(afrag, bfrag, acc[nt], 0, 0, 0);
    }
  }
#pragma unroll
  for (int nt = 0; nt < 4; nt++)
#pragma unroll
    for (int reg = 0; reg < 4; reg++)
      red[wave][nt * 4 + reg][lane] = acc[nt][reg];
  __syncthreads();
  int nt2 = threadIdx.x >> 6;
  int lane2 = threadIdx.x & 63;
  int quad2 = lane2 >> 4, mn2 = lane2 & 15;
#pragma unroll
  for (int reg = 0; reg < 4; reg++) {
    int idx = nt2 * 4 + reg;
    float v = red[0][idx][lane2] + red[1][idx][lane2]
            + red[2][idx][lane2] + red[3][idx][lane2];
    int s = s0 + quad2 * 4 + reg;
    int col = colTile * 64 + nt2 * 16 + mn2;
    if (s < sCount)
      h[(size_t)s * D_HID + col] = fmaxf(v + b1[col], 0.0f);
  }
}

// Layer-2 scatter: re-scan edges; pooled-dst hits (~8k) scatter h rows.
__global__ __launch_bounds__(256) void k_scatter2(
    const int* __restrict__ EI, const int* __restrict__ ET,
    const unsigned* __restrict__ pBit, const int* __restrict__ pId,
    const int* __restrict__ sId, const float* __restrict__ h,
    float* __restrict__ agg2, float* __restrict__ cnt2) {
  __shared__ int2 hits[CHUNK];
  __shared__ int lcnt;
  int tid = threadIdx.x;
  int nChunks = (N_EDGES + CHUNK - 1) / CHUNK;
  for (int c = blockIdx.x; c < nChunks; c += gridDim.x) {
    if (tid == 0) lcnt = 0;
    __syncthreads();
    int e0 = c * CHUNK + tid * 4;
    if (e0 + 3 < N_EDGES) {
      int4 d4 = *(const int4*)(EI + N_EDGES + e0);
      int d[4] = {d4.x, d4.y, d4.z, d4.w};
#pragma unroll
      for (int i = 0; i < 4; i++) {
        int dst = d[i];
        if ((pBit[dst >> 5] >> (dst & 31)) & 1u) {
          int e = e0 + i;
          int code = ET[e] * N_POOL + (pId[dst] - 1);
          int sl = sId[EI[e]] - 1;
          atomAddF(&cnt2[code], 1.0f);
          int p = atomicAdd(&lcnt, 1);
          hits[p] = make_int2(sl, code);
        }
      }
    }
    __syncthreads();
    int nh = lcnt;
    int wid = tid >> 6, lane = tid & 63;
    for (int i = wid; i < nh; i += 4) {
      int2 sc = hits[i];
      const float* hr = h + (size_t)sc.x * D_HID;
      float* ar = agg2 + (size_t)sc.y * D_HID;
      atomAddF(&ar[lane],      hr[lane]);
      atomAddF(&ar[lane + 64], hr[lane + 64]);
    }
    __syncthreads();
  }
}

// Layer-2 GEMM per pooled node, 4-way K-split + LDS reduce.
__global__ __launch_bounds__(256) void k_gemm2(
    const float* __restrict__ W2, const float* __restrict__ root2,
    const float* __restrict__ b2, const float* __restrict__ agg2,
    const float* __restrict__ cnt2, const int* __restrict__ pNodes,
    const int* __restrict__ sId, const int* __restrict__ ctr,
    const float* __restrict__ h, float* __restrict__ emb) {
  __shared__ float a[N_REL * D_HID + D_HID];  // 1152
  __shared__ float inv[N_REL];
  __shared__ float partial[256];
  int pl = blockIdx.x;
  if (pl >= ctr[0]) return;
  int tid = threadIdx.x;
  if (tid < N_REL) inv[tid] = 1.0f / fmaxf(cnt2[tid * N_POOL + pl], 1.0f);
  __syncthreads();
  for (int k = tid; k < 1024; k += 256) {
    int r = k >> 7, d = k & 127;
    a[k] = agg2[(size_t)(r * N_POOL + pl) * D_HID + d] * inv[r];
  }
  if (tid < 128) {
    int slp = sId[pNodes[pl]] - 1;
    a[1024 + tid] = h[(size_t)slp * D_HID + tid];
  }
  __syncthreads();
  int ksl = tid >> 6, c = tid & 63;
  int lo = ksl * 288, hi = lo + 288;
  float acc = 0.0f;
  int hiW = (hi < 1024) ? hi : 1024;
#pragma unroll 4
  for (int k = lo; k < hiW; k++) acc += a[k] * W2[(size_t)k * D_OUT + c];
  int loR = (lo > 1024) ? lo : 1024;
#pragma unroll 4
  for (int k = loR; k < hi; k++) acc += a[k] * root2[(size_t)(k - 1024) * D_OUT + c];
  partial[tid] = acc;
  __syncthreads();
  if (tid < 64) {
    float r = partial[tid] + partial[tid + 64] + partial[tid + 128] + partial[tid + 192];
    emb[(size_t)pl * D_OUT + tid] = r + b2[tid];
  }
}

// Weighted pooling.
__global__ __launch_bounds__(256) void k_pool(
    const float* __restrict__ x, const int* __restrict__ pool,
    const int* __restrict__ pId, const float* __restrict__ emb,
    float* __restrict__ out) {
  __shared__ float ew[N_POOL];
  __shared__ int pls[N_POOL];
  int tid = threadIdx.x;
  int node = pool[tid];
  const float* xr = x + (size_t)node * D_IN;
  ew[tid] = 4.0f * xr[0] + 1.0f * xr[1] + 2.0f * xr[2];
  pls[tid] = pId[node] - 1;
  __syncthreads();
  if (tid < D_OUT) {
    float sw = 0.0f;
    for (int j = 0; j < N_POOL; j++) sw += ew[j];
    float acc = 0.0f;
    for (int j = 0; j < N_POOL; j++) acc += ew[j] * emb[(size_t)pls[j] * D_OUT + tid];
    out[tid] = acc / (sw + 1e-9f);
  }
}

extern "C" void kernel_launch(void* const* d_in, const int* in_sizes, int n_in,
                              void* d_out, int out_size, void* d_ws, size_t ws_size,
                              hipStream_t stream) {
  const float* x     = (const float*)d_in[0];
  const int*   EI    = (const int*)  d_in[1];
  const int*   ET    = (const int*)  d_in[2];
  const int*   pool  = (const int*)  d_in[3];
  const float* W1    = (const float*)d_in[4];
  const float* root1 = (const float*)d_in[5];
  const float* b1    = (const float*)d_in[6];
  const float* W2    = (const float*)d_in[7];
  const float* root2 = (const float*)d_in[8];
  const float* b2    = (const float*)d_in[9];
  float* out = (float*)d_out;

  float* ws = (float*)d_ws;
  int*      cntArr  = (int*)(ws + OFF_CNTA);
  int*      fillCtr = (int*)(ws + OFF_FILLC);
  float*    agg2    = ws + OFF_AGG2;
  float*    cnt2    = ws + OFF_CNT2;
  unsigned* pBit    = (unsigned*)(ws + OFF_PBIT);
  unsigned* sBit    = (unsigned*)(ws + OFF_SBIT);
  int*      ctr     = (int*)(ws + OFF_CTR);
  int*      ptrA    = (int*)(ws + OFF_PTRA);
  int*      bsum    = (int*)(ws + OFF_BSUM);
  int*      pId     = (int*)(ws + OFF_PID);
  int*      sId     = (int*)(ws + OFF_SID);
  int*      pNodes  = (int*)(ws + OFF_PNODES);
  int*      sNodes  = (int*)(ws + OFF_SNODES);
  int*      srcSlot = (int*)(ws + OFF_SRCSLOT);
  unsigned* agg1b   = (unsigned*)(ws + OFF_AGG1B);
  unsigned* xall    = (unsigned*)(ws + OFF_XALL);
  unsigned short* Wt = (unsigned short*)(ws + OFF_WT);
  float*    h       = ws + OFF_H;
  float*    emb     = ws + OFF_EMB;

  k_zero<<<512, 256, 0, stream>>>((float4*)ws, (long)(ZERO_ELEMS / 4));
  k_mark<<<1, 256, 0, stream>>>(pool, pBit, sBit, ctr);
  k_pass1<<<(N_EDGES / 4 + 255) / 256, 256, 0, stream>>>(EI, pBit, sBit);
  k_compactS<<<(N_NODES + 255) / 256, 256, 0, stream>>>(sBit, pBit, sId, sNodes, pId, pNodes, ctr);
  k_count<<<(N_EDGES / 4 + 255) / 256, 256, 0, stream>>>(EI, ET, sBit, sId, cntArr);
  k_scanA<<<NSEG / 1024, 256, 0, stream>>>(cntArr, ptrA, bsum);
  k_scanBC<<<NSEG / 256, 256, 0, stream>>>(ptrA, bsum);
  k_fill<<<(N_EDGES / 4 + 255) / 256, 256, 0, stream>>>(EI, ET, sBit, sId, ptrA, fillCtr, srcSlot);
  k_prep<<<288 + (N_NODES + 3) / 4, 256, 0, stream>>>(W1, root1, Wt, x, xall);
  k_gather<<<NSEG / 4, 256, 0, stream>>>(ptrA, cntArr, srcSlot, xall, ctr, agg1b);
  k_gemm1<<<dim3(CAP_S / 16, 2), 256, 0, stream>>>(
      (const unsigned short*)agg1b, (const unsigned short*)xall, Wt, b1, sNodes, ctr, h);
  k_scatter2<<<1024, 256, 0, stream>>>(EI, ET, pBit, pId, sId, h, agg2, cnt2);
  k_gemm2<<<N_POOL, 256, 0, stream>>>(W2, root2, b2, agg2, cnt2, pNodes, sId, ctr, h, emb);
  k_pool<<<1, 256, 0, stream>>>(x, pool, pId, emb, out);
}

// Round 8
// 212.982 us; speedup vs baseline: 4.0011x; 1.1074x over previous
//
#include <hip/hip_runtime.h>

// Problem constants (fixed by the reference setup_inputs).
#define N_NODES 50000
#define N_EDGES 1600000
#define N_REL   8
#define D_IN    128
#define D_HID   128
#define D_OUT   64
#define N_POOL  256

// Sparse dependency cone capacities (fixed seed; expected |S|~7700,
// edges-into-S ~250k; CAP_S has >1.5x margin, writes clamped).
#define CAP_S   12288
#define NSEG    (N_REL * CAP_S)     // 98304 segments; encoding seg = s*8 + r
#define BUCKET  32                  // per-segment edge capacity; deg|(dst,rel) ~ Poisson(4),
                                    // P(>32) ~ 1e-19 per segment; writes clamped anyway
#define CHUNK   1024

typedef short v8s __attribute__((ext_vector_type(8)));
typedef float v4f __attribute__((ext_vector_type(4)));

// ---- workspace layout (element offsets, 4B units) ----
// Zeroed by k_init grid-stride:
constexpr size_t OFF_FILLC  = 0;                       // NSEG int (bucket counts)
constexpr size_t OFF_AGG2   = OFF_FILLC + NSEG;        // 8*256*128 fp32
constexpr size_t OFF_CNT2   = OFF_AGG2 + (size_t)N_REL * N_POOL * D_HID;  // 2048
constexpr size_t ZERO_ELEMS = OFF_CNT2 + 2048;         // 362,496 (div by 4)
// Zeroed by block 0 of k_init:
constexpr size_t OFF_PBIT   = ZERO_ELEMS;              // 2048 u32
constexpr size_t OFF_SBIT   = OFF_PBIT + 2048;         // 2048 u32
constexpr size_t OFF_CTR    = OFF_SBIT + 2048;         // 8 int  [0]=pCount [1]=sCount
// Write-before-read:
constexpr size_t OFF_PID    = OFF_CTR + 8;             // N_NODES int
constexpr size_t OFF_SID    = OFF_PID + N_NODES;       // N_NODES int
constexpr size_t OFF_PNODES = OFF_SID + N_NODES;       // 256 int
constexpr size_t OFF_SNODES = OFF_PNODES + N_POOL;     // CAP_S int
constexpr size_t OFF_SRCSLOT= OFF_SNODES + CAP_S;      // NSEG*BUCKET int
constexpr size_t OFF_AGG1B  = OFF_SRCSLOT + (size_t)NSEG * BUCKET;  // NSEG*64 u32
constexpr size_t OFF_XALL   = OFF_AGG1B + (size_t)NSEG * 64;        // N_NODES*64 u32
constexpr size_t OFF_WT     = OFF_XALL + (size_t)N_NODES * 64;      // 1152*128 bf16
constexpr size_t OFF_H      = OFF_WT + (size_t)1152 * 128 / 2;      // CAP_S*128 fp32
constexpr size_t OFF_EMB    = OFF_H + (size_t)CAP_S * D_HID;        // 256*64 fp32
constexpr size_t TOTAL_ELEMS= OFF_EMB + (size_t)N_POOL * D_OUT;     // ~59.5 MB

__device__ __forceinline__ void atomAddF(float* p, float v) { unsafeAtomicAdd(p, v); }

__device__ __forceinline__ unsigned short f2bf(float f) {   // RNE fp32 -> bf16
  union { float f; unsigned u; } v; v.f = f;
  unsigned r = v.u + 0x7FFFu + ((v.u >> 16) & 1u);
  return (unsigned short)(r >> 16);
}
__device__ __forceinline__ float bfLo(unsigned v) { return __uint_as_float(v << 16); }
__device__ __forceinline__ float bfHi(unsigned v) { return __uint_as_float(v & 0xFFFF0000u); }

// Fused init: zero bucket-counts/agg2/cnt2 (grid-stride), zero+mark bitmaps
// (block 0), pack Wt (blocks 1..72), convert x->bf16 (grid-stride).
__global__ __launch_bounds__(256) void k_init(
    const int* __restrict__ pool, const float* __restrict__ x,
    const float* __restrict__ W1, const float* __restrict__ root1,
    float* __restrict__ ws) {
  unsigned* pBit = (unsigned*)(ws + OFF_PBIT);
  unsigned* sBit = (unsigned*)(ws + OFF_SBIT);
  int*      ctr  = (int*)(ws + OFF_CTR);
  unsigned* xall = (unsigned*)(ws + OFF_XALL);
  unsigned short* Wt = (unsigned short*)(ws + OFF_WT);
  int tid = threadIdx.x, bid = blockIdx.x;
  int gtid = bid * 256 + tid, gthr = gridDim.x * 256;
  int wave = tid >> 6, lane = tid & 63;

  float4 z = {0.f, 0.f, 0.f, 0.f};
  for (int i = gtid; i < (int)(ZERO_ELEMS / 4); i += gthr) ((float4*)ws)[i] = z;

  if (bid == 0) {
    for (int i = tid; i < 2048; i += 256) { pBit[i] = 0u; sBit[i] = 0u; }
    if (tid < 8) ctr[tid] = 0;
    __syncthreads();
    int node = pool[tid];
    unsigned bit = 1u << (node & 31);
    atomicOr(&pBit[node >> 5], bit);
    atomicOr(&sBit[node >> 5], bit);
  }

  int gw = (bid - 1) * 4 + wave;          // Wt pack on blocks 1..72
  if (bid >= 1 && gw < 288) {
    int kt = gw >> 3, nt = gw & 7;
    int k0 = kt * 32 + ((lane >> 4) << 3);
    int n = nt * 16 + (lane & 15);
    v8s frag;
#pragma unroll
    for (int j = 0; j < 8; j++) {
      int kg = k0 + j;
      float v = (kg < 1024) ? W1[(size_t)kg * D_HID + n]
                            : root1[(size_t)(kg - 1024) * D_HID + n];
      frag[j] = (short)f2bf(v);
    }
    ((v8s*)Wt)[gw * 64 + lane] = frag;
  }

  for (int i = gtid; i < N_NODES * 64; i += gthr) {   // x -> packed bf16
    float2 v = ((const float2*)x)[i];
    xall[i] = ((unsigned)f2bf(v.y) << 16) | f2bf(v.x);
  }
}

// Pass 1: mark sources of pooled-dst edges into sBit.
__global__ __launch_bounds__(256) void k_pass1(
    const int* __restrict__ EI, const unsigned* __restrict__ pBit, unsigned* sBit) {
  int idx = blockIdx.x * 256 + threadIdx.x;
  if (idx >= N_EDGES / 4) return;
  int4 d4 = ((const int4*)(EI + N_EDGES))[idx];
  int d[4] = {d4.x, d4.y, d4.z, d4.w};
#pragma unroll
  for (int i = 0; i < 4; i++) {
    int dst = d[i];
    if ((pBit[dst >> 5] >> (dst & 31)) & 1u) {
      int src = EI[idx * 4 + i];
      atomicOr(&sBit[src >> 5], 1u << (src & 31));
    }
  }
}

// Number S (block-aggregated atomic) and P (wave-aggregated).
__global__ __launch_bounds__(256) void k_compactS(
    const unsigned* __restrict__ sBit, const unsigned* __restrict__ pBit,
    int* sId, int* sNodes, int* pId, int* pNodes, int* ctr) {
  __shared__ int wcnt[4];
  __shared__ int sbase;
  int tid = threadIdx.x, wave = tid >> 6, lane = tid & 63;
  int node = blockIdx.x * 256 + tid;
  bool sp = (node < N_NODES) && ((sBit[node >> 5] >> (node & 31)) & 1u);
  unsigned long long m = __ballot(sp);
  if (lane == 0) wcnt[wave] = __popcll(m);
  __syncthreads();
  if (tid == 0) {
    int tot = wcnt[0] + wcnt[1] + wcnt[2] + wcnt[3];
    sbase = tot ? atomicAdd(&ctr[1], tot) : 0;
  }
  __syncthreads();
  if (sp) {
    int off = sbase;
    for (int w2 = 0; w2 < wave; w2++) off += wcnt[w2];
    int id = off + __popcll(m & ((1ull << lane) - 1ull));
    if (id < CAP_S) { sId[node] = id + 1; sNodes[id] = node; }
    else sId[node] = 0;
  }
  bool pp = (node < N_NODES) && ((pBit[node >> 5] >> (node & 31)) & 1u);
  unsigned long long pm = __ballot(pp);
  if (pm) {
    int leader = __ffsll(pm) - 1;
    int base = 0;
    if (lane == leader) base = atomicAdd(&ctr[0], __popcll(pm));
    base = __shfl(base, leader);
    if (pp) {
      int id = base + __popcll(pm & ((1ull << lane) - 1ull));
      pId[node] = id + 1;
      pNodes[id] = node;
    }
  }
}

// Fill bucket CSR: srcSlot[seg*BUCKET + cursor] = src (no scans needed).
__global__ __launch_bounds__(256) void k_fill(
    const int* __restrict__ EI, const int* __restrict__ ET,
    const unsigned* __restrict__ sBit, const int* __restrict__ sId,
    int* __restrict__ fillCtr, int* __restrict__ srcSlot) {
  int idx = blockIdx.x * 256 + threadIdx.x;
  if (idx >= N_EDGES / 4) return;
  int4 d4 = ((const int4*)(EI + N_EDGES))[idx];
  int4 t4 = ((const int4*)ET)[idx];
  int4 s4 = ((const int4*)EI)[idx];
  int d[4] = {d4.x, d4.y, d4.z, d4.w};
  int t[4] = {t4.x, t4.y, t4.z, t4.w};
  int s[4] = {s4.x, s4.y, s4.z, s4.w};
#pragma unroll
  for (int i = 0; i < 4; i++) {
    int dst = d[i];
    if ((sBit[dst >> 5] >> (dst & 31)) & 1u) {
      int sp = sId[dst];
      if (sp > 0) {
        int seg = ((sp - 1) << 3) + t[i];
        int slot = atomicAdd(&fillCtr[seg], 1);
        if (slot < BUCKET) srcSlot[seg * BUCKET + slot] = s[i];
      }
    }
  }
}

// Gather-reduce: one wave per segment; bf16 row gathers, 4 in flight; write
// MEAN as packed bf16. Active segments contiguous in [0, 8*sCount).
__global__ __launch_bounds__(256) void k_gather(
    const int* __restrict__ fillCtr, const int* __restrict__ srcSlot,
    const unsigned* __restrict__ xall, const int* __restrict__ ctr,
    unsigned* __restrict__ agg1b) {
  int w = (blockIdx.x << 2) + (threadIdx.x >> 6);
  if (w >= (ctr[1] << 3)) return;
  int lane = threadIdx.x & 63;
  int cnt = fillCtr[w];
  if (cnt > BUCKET) cnt = BUCKET;
  const int* slot = srcSlot + w * BUCKET;
  float a0 = 0.f, a1 = 0.f;
  int i = 0;
  for (; i + 4 <= cnt; i += 4) {
    int s0 = slot[i + 0];
    int s1 = slot[i + 1];
    int s2 = slot[i + 2];
    int s3 = slot[i + 3];
    unsigned v0 = xall[(size_t)s0 * 64 + lane];
    unsigned v1 = xall[(size_t)s1 * 64 + lane];
    unsigned v2 = xall[(size_t)s2 * 64 + lane];
    unsigned v3 = xall[(size_t)s3 * 64 + lane];
    a0 += (bfLo(v0) + bfLo(v1)) + (bfLo(v2) + bfLo(v3));
    a1 += (bfHi(v0) + bfHi(v1)) + (bfHi(v2) + bfHi(v3));
  }
  for (; i < cnt; i++) {
    unsigned v = xall[(size_t)slot[i] * 64 + lane];
    a0 += bfLo(v);
    a1 += bfHi(v);
  }
  float inv = 1.0f / fmaxf((float)cnt, 1.0f);
  agg1b[(size_t)w * 64 + lane] = ((unsigned)f2bf(a1 * inv) << 16) | f2bf(a0 * inv);
}

// Layer-1 GEMM via bf16 MFMA 16x16x32, K-split x4 + N-split x2.
__global__ __launch_bounds__(256) void k_gemm1(
    const unsigned short* __restrict__ agg1b, const unsigned short* __restrict__ xall,
    const unsigned short* __restrict__ Wt, const float* __restrict__ b1,
    const int* __restrict__ sNodes, const int* __restrict__ ctr,
    float* __restrict__ h) {
  __shared__ float red[4][16][64];           // 16 KB
  int sCount = ctr[1];
  int s0 = blockIdx.x * 16;
  if (s0 >= sCount) return;
  int colTile = blockIdx.y;                  // 0..1
  int wave = threadIdx.x >> 6, lane = threadIdx.x & 63;
  int quad = lane >> 4, mn = lane & 15;
  int srow = s0 + mn;
  int g = (srow < sCount) ? sNodes[srow] : 0;
  v4f acc[4];
#pragma unroll
  for (int i = 0; i < 4; i++) acc[i] = (v4f){0.f, 0.f, 0.f, 0.f};
  const v8s* WtF = (const v8s*)Wt;
  int kt0 = wave * 9, kt1 = kt0 + 9;
  for (int kt = kt0; kt < kt1; kt++) {
    const unsigned short* aptr;
    if (kt < 32) {                           // mean part: k = r*128 + d
      int r = kt >> 2;
      int d0 = (kt & 3) * 32 + quad * 8;
      aptr = agg1b + ((size_t)((srow << 3) + r) * 128 + d0);
    } else {                                 // root part from xall
      int d0 = (kt - 32) * 32 + quad * 8;
      aptr = xall + ((size_t)g * 128 + d0);
    }
    v8s afrag = *(const v8s*)aptr;
    const v8s* wrow = WtF + (size_t)(kt * 8 + colTile * 4) * 64 + lane;
#pragma unroll
    for (int nt = 0; nt < 4; nt++) {
      v8s bfrag = wrow[nt * 64];
      acc[nt] = __builtin_amdgcn_mfma_f32_16x16x32_bf16(afrag, bfrag, acc[nt], 0, 0, 0);
    }
  }
#pragma unroll
  for (int nt = 0; nt < 4; nt++)
#pragma unroll
    for (int reg = 0; reg < 4; reg++)
      red[wave][nt * 4 + reg][lane] = acc[nt][reg];
  __syncthreads();
  int nt2 = threadIdx.x >> 6;
  int lane2 = threadIdx.x & 63;
  int quad2 = lane2 >> 4, mn2 = lane2 & 15;
#pragma unroll
  for (int reg = 0; reg < 4; reg++) {
    int idx = nt2 * 4 + reg;
    float v = red[0][idx][lane2] + red[1][idx][lane2]
            + red[2][idx][lane2] + red[3][idx][lane2];
    int s = s0 + quad2 * 4 + reg;
    int col = colTile * 64 + nt2 * 16 + mn2;
    if (s < sCount)
      h[(size_t)s * D_HID + col] = fmaxf(v + b1[col], 0.0f);
  }
}

// Layer-2 scatter: re-scan edges; pooled-dst hits (~8k) scatter h rows.
__global__ __launch_bounds__(256) void k_scatter2(
    const int* __restrict__ EI, const int* __restrict__ ET,
    const unsigned* __restrict__ pBit, const int* __restrict__ pId,
    const int* __restrict__ sId, const float* __restrict__ h,
    float* __restrict__ agg2, float* __restrict__ cnt2) {
  __shared__ int2 hits[CHUNK];
  __shared__ int lcnt;
  int tid = threadIdx.x;
  int nChunks = (N_EDGES + CHUNK - 1) / CHUNK;
  for (int c = blockIdx.x; c < nChunks; c += gridDim.x) {
    if (tid == 0) lcnt = 0;
    __syncthreads();
    int e0 = c * CHUNK + tid * 4;
    if (e0 + 3 < N_EDGES) {
      int4 d4 = *(const int4*)(EI + N_EDGES + e0);
      int d[4] = {d4.x, d4.y, d4.z, d4.w};
#pragma unroll
      for (int i = 0; i < 4; i++) {
        int dst = d[i];
        if ((pBit[dst >> 5] >> (dst & 31)) & 1u) {
          int e = e0 + i;
          int code = ET[e] * N_POOL + (pId[dst] - 1);
          int sl = sId[EI[e]] - 1;
          atomAddF(&cnt2[code], 1.0f);
          int p = atomicAdd(&lcnt, 1);
          hits[p] = make_int2(sl, code);
        }
      }
    }
    __syncthreads();
    int nh = lcnt;
    int wid = tid >> 6, lane = tid & 63;
    for (int i = wid; i < nh; i += 4) {
      int2 sc = hits[i];
      const float* hr = h + (size_t)sc.x * D_HID;
      float* ar = agg2 + (size_t)sc.y * D_HID;
      atomAddF(&ar[lane],      hr[lane]);
      atomAddF(&ar[lane + 64], hr[lane + 64]);
    }
    __syncthreads();
  }
}

// Layer-2 GEMM per pooled node, 4-way K-split + LDS reduce.
__global__ __launch_bounds__(256) void k_gemm2(
    const float* __restrict__ W2, const float* __restrict__ root2,
    const float* __restrict__ b2, const float* __restrict__ agg2,
    const float* __restrict__ cnt2, const int* __restrict__ pNodes,
    const int* __restrict__ sId, const int* __restrict__ ctr,
    const float* __restrict__ h, float* __restrict__ emb) {
  __shared__ float a[N_REL * D_HID + D_HID];  // 1152
  __shared__ float inv[N_REL];
  __shared__ float partial[256];
  int pl = blockIdx.x;
  if (pl >= ctr[0]) return;
  int tid = threadIdx.x;
  if (tid < N_REL) inv[tid] = 1.0f / fmaxf(cnt2[tid * N_POOL + pl], 1.0f);
  __syncthreads();
  for (int k = tid; k < 1024; k += 256) {
    int r = k >> 7, d = k & 127;
    a[k] = agg2[(size_t)(r * N_POOL + pl) * D_HID + d] * inv[r];
  }
  if (tid < 128) {
    int slp = sId[pNodes[pl]] - 1;
    a[1024 + tid] = h[(size_t)slp * D_HID + tid];
  }
  __syncthreads();
  int ksl = tid >> 6, c = tid & 63;
  int lo = ksl * 288, hi = lo + 288;
  float acc = 0.0f;
  int hiW = (hi < 1024) ? hi : 1024;
#pragma unroll 4
  for (int k = lo; k < hiW; k++) acc += a[k] * W2[(size_t)k * D_OUT + c];
  int loR = (lo > 1024) ? lo : 1024;
#pragma unroll 4
  for (int k = loR; k < hi; k++) acc += a[k] * root2[(size_t)(k - 1024) * D_OUT + c];
  partial[tid] = acc;
  __syncthreads();
  if (tid < 64) {
    float r = partial[tid] + partial[tid + 64] + partial[tid + 128] + partial[tid + 192];
    emb[(size_t)pl * D_OUT + tid] = r + b2[tid];
  }
}

// Weighted pooling.
__global__ __launch_bounds__(256) void k_pool(
    const float* __restrict__ x, const int* __restrict__ pool,
    const int* __restrict__ pId, const float* __restrict__ emb,
    float* __restrict__ out) {
  __shared__ float ew[N_POOL];
  __shared__ int pls[N_POOL];
  int tid = threadIdx.x;
  int node = pool[tid];
  const float* xr = x + (size_t)node * D_IN;
  ew[tid] = 4.0f * xr[0] + 1.0f * xr[1] + 2.0f * xr[2];
  pls[tid] = pId[node] - 1;
  __syncthreads();
  if (tid < D_OUT) {
    float sw = 0.0f;
    for (int j = 0; j < N_POOL; j++) sw += ew[j];
    float acc = 0.0f;
    for (int j = 0; j < N_POOL; j++) acc += ew[j] * emb[(size_t)pls[j] * D_OUT + tid];
    out[tid] = acc / (sw + 1e-9f);
  }
}

extern "C" void kernel_launch(void* const* d_in, const int* in_sizes, int n_in,
                              void* d_out, int out_size, void* d_ws, size_t ws_size,
                              hipStream_t stream) {
  const float* x     = (const float*)d_in[0];
  const int*   EI    = (const int*)  d_in[1];
  const int*   ET    = (const int*)  d_in[2];
  const int*   pool  = (const int*)  d_in[3];
  const float* W1    = (const float*)d_in[4];
  const float* root1 = (const float*)d_in[5];
  const float* b1    = (const float*)d_in[6];
  const float* W2    = (const float*)d_in[7];
  const float* root2 = (const float*)d_in[8];
  const float* b2    = (const float*)d_in[9];
  float* out = (float*)d_out;
  float* ws  = (float*)d_ws;

  int*      fillCtr = (int*)(ws + OFF_FILLC);
  float*    agg2    = ws + OFF_AGG2;
  float*    cnt2    = ws + OFF_CNT2;
  unsigned* pBit    = (unsigned*)(ws + OFF_PBIT);
  unsigned* sBit    = (unsigned*)(ws + OFF_SBIT);
  int*      ctr     = (int*)(ws + OFF_CTR);
  int*      pId     = (int*)(ws + OFF_PID);
  int*      sId     = (int*)(ws + OFF_SID);
  int*      pNodes  = (int*)(ws + OFF_PNODES);
  int*      sNodes  = (int*)(ws + OFF_SNODES);
  int*      srcSlot = (int*)(ws + OFF_SRCSLOT);
  unsigned* agg1b   = (unsigned*)(ws + OFF_AGG1B);
  unsigned* xall    = (unsigned*)(ws + OFF_XALL);
  unsigned short* Wt = (unsigned short*)(ws + OFF_WT);
  float*    h       = ws + OFF_H;
  float*    emb     = ws + OFF_EMB;

  k_init<<<1024, 256, 0, stream>>>(pool, x, W1, root1, ws);
  k_pass1<<<(N_EDGES / 4 + 255) / 256, 256, 0, stream>>>(EI, pBit, sBit);
  k_compactS<<<(N_NODES + 255) / 256, 256, 0, stream>>>(sBit, pBit, sId, sNodes, pId, pNodes, ctr);
  k_fill<<<(N_EDGES / 4 + 255) / 256, 256, 0, stream>>>(EI, ET, sBit, sId, fillCtr, srcSlot);
  k_gather<<<NSEG / 4, 256, 0, stream>>>(fillCtr, srcSlot, xall, ctr, agg1b);
  k_gemm1<<<dim3(CAP_S / 16, 2), 256, 0, stream>>>(
      (const unsigned short*)agg1b, (const unsigned short*)xall, Wt, b1, sNodes, ctr, h);
  k_scatter2<<<1024, 256, 0, stream>>>(EI, ET, pBit, pId, sId, h, agg2, cnt2);
  k_gemm2<<<N_POOL, 256, 0, stream>>>(W2, root2, b2, agg2, cnt2, pNodes, sId, ctr, h, emb);
  k_pool<<<1, 256, 0, stream>>>(x, pool, pId, emb, out);
}

// Round 9
// 206.886 us; speedup vs baseline: 4.1190x; 1.0295x over previous
//
#include <hip/hip_runtime.h>

// Problem constants (fixed by the reference setup_inputs).
#define N_NODES 50000
#define N_EDGES 1600000
#define N_REL   8
#define D_IN    128
#define D_HID   128
#define D_OUT   64
#define N_POOL  256

// Sparse dependency cone capacities (fixed seed; expected |S|~7700,
// edges-into-S ~250k; CAP_S has >1.5x margin, writes clamped).
#define CAP_S   12288
#define NSEG    (N_REL * CAP_S)     // 98304 layer-1 segments; seg = s*8 + r
#define BUCKET  32                  // layer-1 per-segment cap; deg ~ Poisson(4), P(>32)~1e-19
#define BUCKET2 32                  // layer-2 per-code cap; deg ~ Poisson(4)
#define NCODE   (N_REL * N_POOL)    // 2048 layer-2 codes; code = r*256 + pl

typedef short v8s __attribute__((ext_vector_type(8)));
typedef float v4f __attribute__((ext_vector_type(4)));

// ---- workspace layout (element offsets, 4B units) ----
// Zeroed by k_init grid-stride:
constexpr size_t OFF_FILLC  = 0;                       // NSEG int (L1 bucket counts)
constexpr size_t OFF_FILLC2 = OFF_FILLC + NSEG;        // NCODE int (L2 bucket counts)
constexpr size_t ZERO_ELEMS = OFF_FILLC2 + NCODE;      // 100,352 (div by 4)
// Zeroed by block 0 of k_init:
constexpr size_t OFF_PBIT   = ZERO_ELEMS;              // 2048 u32
constexpr size_t OFF_SBIT   = OFF_PBIT + 2048;         // 2048 u32
constexpr size_t OFF_CTR    = OFF_SBIT + 2048;         // 8 int [0]=pCount [1]=sCount [2]=done
// Write-before-read:
constexpr size_t OFF_PID    = OFF_CTR + 8;             // N_NODES int
constexpr size_t OFF_SID    = OFF_PID + N_NODES;       // N_NODES int
constexpr size_t OFF_PNODES = OFF_SID + N_NODES;       // 256 int
constexpr size_t OFF_SNODES = OFF_PNODES + N_POOL;     // CAP_S int
constexpr size_t OFF_SRCSLOT= OFF_SNODES + CAP_S;      // NSEG*BUCKET int
constexpr size_t OFF_ESLOT2 = OFF_SRCSLOT + (size_t)NSEG * BUCKET;  // NCODE*BUCKET2 int
constexpr size_t OFF_AGG1B  = OFF_ESLOT2 + (size_t)NCODE * BUCKET2; // NSEG*64 u32
constexpr size_t OFF_XALL   = OFF_AGG1B + (size_t)NSEG * 64;        // N_NODES*64 u32
constexpr size_t OFF_WT     = OFF_XALL + (size_t)N_NODES * 64;      // 1152*128 bf16
constexpr size_t OFF_H      = OFF_WT + (size_t)1152 * 128 / 2;      // CAP_S*128 fp32
constexpr size_t OFF_EMB    = OFF_H + (size_t)CAP_S * D_HID;        // 256*64 fp32
constexpr size_t TOTAL_ELEMS= OFF_EMB + (size_t)N_POOL * D_OUT;     // ~52 MB

__device__ __forceinline__ void atomAddF(float* p, float v) { unsafeAtomicAdd(p, v); }

__device__ __forceinline__ unsigned short f2bf(float f) {   // RNE fp32 -> bf16
  union { float f; unsigned u; } v; v.f = f;
  unsigned r = v.u + 0x7FFFu + ((v.u >> 16) & 1u);
  return (unsigned short)(r >> 16);
}
__device__ __forceinline__ float bfLo(unsigned v) { return __uint_as_float(v << 16); }
__device__ __forceinline__ float bfHi(unsigned v) { return __uint_as_float(v & 0xFFFF0000u); }

// Fused init: zero bucket counts (grid-stride), zero+mark bitmaps + ctr
// (block 0), pack Wt (blocks 1..72), convert x->bf16 (grid-stride).
__global__ __launch_bounds__(256) void k_init(
    const int* __restrict__ pool, const float* __restrict__ x,
    const float* __restrict__ W1, const float* __restrict__ root1,
    float* __restrict__ ws) {
  unsigned* pBit = (unsigned*)(ws + OFF_PBIT);
  unsigned* sBit = (unsigned*)(ws + OFF_SBIT);
  int*      ctr  = (int*)(ws + OFF_CTR);
  unsigned* xall = (unsigned*)(ws + OFF_XALL);
  unsigned short* Wt = (unsigned short*)(ws + OFF_WT);
  int tid = threadIdx.x, bid = blockIdx.x;
  int gtid = bid * 256 + tid, gthr = gridDim.x * 256;
  int wave = tid >> 6, lane = tid & 63;

  float4 z = {0.f, 0.f, 0.f, 0.f};
  for (int i = gtid; i < (int)(ZERO_ELEMS / 4); i += gthr) ((float4*)ws)[i] = z;

  if (bid == 0) {
    for (int i = tid; i < 2048; i += 256) { pBit[i] = 0u; sBit[i] = 0u; }
    if (tid < 8) ctr[tid] = 0;
    __syncthreads();
    int node = pool[tid];
    unsigned bit = 1u << (node & 31);
    atomicOr(&pBit[node >> 5], bit);
    atomicOr(&sBit[node >> 5], bit);
  }

  int gw = (bid - 1) * 4 + wave;          // Wt pack on blocks 1..72
  if (bid >= 1 && gw < 288) {
    int kt = gw >> 3, nt = gw & 7;
    int k0 = kt * 32 + ((lane >> 4) << 3);
    int n = nt * 16 + (lane & 15);
    v8s frag;
#pragma unroll
    for (int j = 0; j < 8; j++) {
      int kg = k0 + j;
      float v = (kg < 1024) ? W1[(size_t)kg * D_HID + n]
                            : root1[(size_t)(kg - 1024) * D_HID + n];
      frag[j] = (short)f2bf(v);
    }
    ((v8s*)Wt)[gw * 64 + lane] = frag;
  }

  for (int i = gtid; i < N_NODES * 64; i += gthr) {   // x -> packed bf16
    float2 v = ((const float2*)x)[i];
    xall[i] = ((unsigned)f2bf(v.y) << 16) | f2bf(v.x);
  }
}

// Pass 1: mark sources of pooled-dst edges into sBit.
__global__ __launch_bounds__(256) void k_pass1(
    const int* __restrict__ EI, const unsigned* __restrict__ pBit, unsigned* sBit) {
  int idx = blockIdx.x * 256 + threadIdx.x;
  if (idx >= N_EDGES / 4) return;
  int4 d4 = ((const int4*)(EI + N_EDGES))[idx];
  int d[4] = {d4.x, d4.y, d4.z, d4.w};
#pragma unroll
  for (int i = 0; i < 4; i++) {
    int dst = d[i];
    if ((pBit[dst >> 5] >> (dst & 31)) & 1u) {
      int src = EI[idx * 4 + i];
      atomicOr(&sBit[src >> 5], 1u << (src & 31));
    }
  }
}

// Number S (block-aggregated atomic) and P (wave-aggregated).
__global__ __launch_bounds__(256) void k_compactS(
    const unsigned* __restrict__ sBit, const unsigned* __restrict__ pBit,
    int* sId, int* sNodes, int* pId, int* pNodes, int* ctr) {
  __shared__ int wcnt[4];
  __shared__ int sbase;
  int tid = threadIdx.x, wave = tid >> 6, lane = tid & 63;
  int node = blockIdx.x * 256 + tid;
  bool sp = (node < N_NODES) && ((sBit[node >> 5] >> (node & 31)) & 1u);
  unsigned long long m = __ballot(sp);
  if (lane == 0) wcnt[wave] = __popcll(m);
  __syncthreads();
  if (tid == 0) {
    int tot = wcnt[0] + wcnt[1] + wcnt[2] + wcnt[3];
    sbase = tot ? atomicAdd(&ctr[1], tot) : 0;
  }
  __syncthreads();
  if (sp) {
    int off = sbase;
    for (int w2 = 0; w2 < wave; w2++) off += wcnt[w2];
    int id = off + __popcll(m & ((1ull << lane) - 1ull));
    if (id < CAP_S) { sId[node] = id + 1; sNodes[id] = node; }
    else sId[node] = 0;
  }
  bool pp = (node < N_NODES) && ((pBit[node >> 5] >> (node & 31)) & 1u);
  unsigned long long pm = __ballot(pp);
  if (pm) {
    int leader = __ffsll(pm) - 1;
    int base = 0;
    if (lane == leader) base = atomicAdd(&ctr[0], __popcll(pm));
    base = __shfl(base, leader);
    if (pp) {
      int id = base + __popcll(pm & ((1ull << lane) - 1ull));
      pId[node] = id + 1;
      pNodes[id] = node;
    }
  }
}

// Fill bucket CSRs: layer-1 (dst in S -> srcSlot by seg) and layer-2
// (dst pooled -> s-local of src by code). One pass over all edges.
__global__ __launch_bounds__(256) void k_fill(
    const int* __restrict__ EI, const int* __restrict__ ET,
    const unsigned* __restrict__ sBit, const unsigned* __restrict__ pBit,
    const int* __restrict__ sId, const int* __restrict__ pId,
    int* __restrict__ fillCtr, int* __restrict__ srcSlot,
    int* __restrict__ fillCtr2, int* __restrict__ eslot2) {
  int idx = blockIdx.x * 256 + threadIdx.x;
  if (idx >= N_EDGES / 4) return;
  int4 d4 = ((const int4*)(EI + N_EDGES))[idx];
  int4 t4 = ((const int4*)ET)[idx];
  int4 s4 = ((const int4*)EI)[idx];
  int d[4] = {d4.x, d4.y, d4.z, d4.w};
  int t[4] = {t4.x, t4.y, t4.z, t4.w};
  int s[4] = {s4.x, s4.y, s4.z, s4.w};
#pragma unroll
  for (int i = 0; i < 4; i++) {
    int dst = d[i];
    if ((sBit[dst >> 5] >> (dst & 31)) & 1u) {
      int sp = sId[dst];
      if (sp > 0) {
        int seg = ((sp - 1) << 3) + t[i];
        int slot = atomicAdd(&fillCtr[seg], 1);
        if (slot < BUCKET) srcSlot[seg * BUCKET + slot] = s[i];
      }
      if ((pBit[dst >> 5] >> (dst & 31)) & 1u) {     // pooled dst (subset of S)
        int code = t[i] * N_POOL + (pId[dst] - 1);
        int sl = sId[s[i]] - 1;                      // src is in S by construction
        if (sl >= 0) {
          int slot = atomicAdd(&fillCtr2[code], 1);
          if (slot < BUCKET2) eslot2[code * BUCKET2 + slot] = sl;
        }
      }
    }
  }
}

// Gather-reduce layer 1: one wave per segment; bf16 row gathers, 4 in flight;
// write MEAN as packed bf16. Active segments contiguous in [0, 8*sCount).
__global__ __launch_bounds__(256) void k_gather(
    const int* __restrict__ fillCtr, const int* __restrict__ srcSlot,
    const unsigned* __restrict__ xall, const int* __restrict__ ctr,
    unsigned* __restrict__ agg1b) {
  int w = (blockIdx.x << 2) + (threadIdx.x >> 6);
  if (w >= (ctr[1] << 3)) return;
  int lane = threadIdx.x & 63;
  int cnt = fillCtr[w];
  if (cnt > BUCKET) cnt = BUCKET;
  const int* slot = srcSlot + w * BUCKET;
  float a0 = 0.f, a1 = 0.f;
  int i = 0;
  for (; i + 4 <= cnt; i += 4) {
    int s0 = slot[i + 0];
    int s1 = slot[i + 1];
    int s2 = slot[i + 2];
    int s3 = slot[i + 3];
    unsigned v0 = xall[(size_t)s0 * 64 + lane];
    unsigned v1 = xall[(size_t)s1 * 64 + lane];
    unsigned v2 = xall[(size_t)s2 * 64 + lane];
    unsigned v3 = xall[(size_t)s3 * 64 + lane];
    a0 += (bfLo(v0) + bfLo(v1)) + (bfLo(v2) + bfLo(v3));
    a1 += (bfHi(v0) + bfHi(v1)) + (bfHi(v2) + bfHi(v3));
  }
  for (; i < cnt; i++) {
    unsigned v = xall[(size_t)slot[i] * 64 + lane];
    a0 += bfLo(v);
    a1 += bfHi(v);
  }
  float inv = 1.0f / fmaxf((float)cnt, 1.0f);
  agg1b[(size_t)w * 64 + lane] = ((unsigned)f2bf(a1 * inv) << 16) | f2bf(a0 * inv);
}

// Layer-1 GEMM via bf16 MFMA 16x16x32, K-split x4 + N-split x2.
__global__ __launch_bounds__(256) void k_gemm1(
    const unsigned short* __restrict__ agg1b, const unsigned short* __restrict__ xall,
    const unsigned short* __restrict__ Wt, const float* __restrict__ b1,
    const int* __restrict__ sNodes, const int* __restrict__ ctr,
    float* __restrict__ h) {
  __shared__ float red[4][16][64];           // 16 KB
  int sCount = ctr[1];
  int s0 = blockIdx.x * 16;
  if (s0 >= sCount) return;
  int colTile = blockIdx.y;                  // 0..1
  int wave = threadIdx.x >> 6, lane = threadIdx.x & 63;
  int quad = lane >> 4, mn = lane & 15;
  int srow = s0 + mn;
  int g = (srow < sCount) ? sNodes[srow] : 0;
  v4f acc[4];
#pragma unroll
  for (int i = 0; i < 4; i++) acc[i] = (v4f){0.f, 0.f, 0.f, 0.f};
  const v8s* WtF = (const v8s*)Wt;
  int kt0 = wave * 9, kt1 = kt0 + 9;
  for (int kt = kt0; kt < kt1; kt++) {
    const unsigned short* aptr;
    if (kt < 32) {                           // mean part: k = r*128 + d
      int r = kt >> 2;
      int d0 = (kt & 3) * 32 + quad * 8;
      aptr = agg1b + ((size_t)((srow << 3) + r) * 128 + d0);
    } else {                                 // root part from xall
      int d0 = (kt - 32) * 32 + quad * 8;
      aptr = xall + ((size_t)g * 128 + d0);
    }
    v8s afrag = *(const v8s*)aptr;
    const v8s* wrow = WtF + (size_t)(kt * 8 + colTile * 4) * 64 + lane;
#pragma unroll
    for (int nt = 0; nt < 4; nt++) {
      v8s bfrag = wrow[nt * 64];
      acc[nt] = __builtin_amdgcn_mfma_f32_16x16x32_bf16(afrag, bfrag, acc[nt], 0, 0, 0);
    }
  }
#pragma unroll
  for (int nt = 0; nt < 4; nt++)
#pragma unroll
    for (int reg = 0; reg < 4; reg++)
      red[wave][nt * 4 + reg][lane] = acc[nt][reg];
  __syncthreads();
  int nt2 = threadIdx.x >> 6;
  int lane2 = threadIdx.x & 63;
  int quad2 = lane2 >> 4, mn2 = lane2 & 15;
#pragma unroll
  for (int reg = 0; reg < 4; reg++) {
    int idx = nt2 * 4 + reg;
    float v = red[0][idx][lane2] + red[1][idx][lane2]
            + red[2][idx][lane2] + red[3][idx][lane2];
    int s = s0 + quad2 * 4 + reg;
    int col = colTile * 64 + nt2 * 16 + mn2;
    if (s < sCount)
      h[(size_t)s * D_HID + col] = fmaxf(v + b1[col], 0.0f);
  }
}

// Layer-2 GEMM per pooled node: gathers its own 8 code-buckets into LDS
// (mean applied in-register), then 4-way K-split GEMM. The LAST block to
// finish (device-scope done counter) performs the weighted pooling.
__global__ __launch_bounds__(256) void k_gemm2(
    const float* __restrict__ W2, const float* __restrict__ root2,
    const float* __restrict__ b2,
    const int* __restrict__ fillCtr2, const int* __restrict__ eslot2,
    const int* __restrict__ pNodes, const int* __restrict__ pId,
    const int* __restrict__ sId, int* __restrict__ ctr,
    const float* __restrict__ h, const float* __restrict__ x,
    const int* __restrict__ pool, float* __restrict__ emb,
    float* __restrict__ out) {
  __shared__ float a[N_REL * D_HID + D_HID];  // 1152
  __shared__ float partial[256];
  __shared__ float ew[N_POOL];
  __shared__ int pls[N_POOL];
  __shared__ int flag;
  int pl = blockIdx.x;
  int tid = threadIdx.x, wave = tid >> 6, lane = tid & 63;
  int pCount = ctr[0];
  if (pl < pCount) {
    // gather this node's 8 relation-buckets: wave handles codes r=2w, 2w+1
#pragma unroll
    for (int rr = 0; rr < 2; rr++) {
      int r = wave * 2 + rr;
      int code = r * N_POOL + pl;
      int cnt = fillCtr2[code]; if (cnt > BUCKET2) cnt = BUCKET2;
      const int* sl = eslot2 + code * BUCKET2;
      float s0 = 0.f, s1 = 0.f;
      for (int i = 0; i < cnt; i++) {
        float2 v = ((const float2*)h)[(size_t)sl[i] * 64 + lane];
        s0 += v.x; s1 += v.y;
      }
      float inv = 1.0f / fmaxf((float)cnt, 1.0f);
      a[r * 128 + lane * 2]     = s0 * inv;
      a[r * 128 + lane * 2 + 1] = s1 * inv;
    }
    if (tid < 128) {
      int slp = sId[pNodes[pl]] - 1;
      a[1024 + tid] = h[(size_t)slp * D_HID + tid];
    }
    __syncthreads();
    int lo = wave * 288, hi = lo + 288;
    float acc = 0.0f;
    int hiW = (hi < 1024) ? hi : 1024;
#pragma unroll 4
    for (int k = lo; k < hiW; k++) acc += a[k] * W2[(size_t)k * D_OUT + lane];
    int loR = (lo > 1024) ? lo : 1024;
#pragma unroll 4
    for (int k = loR; k < hi; k++) acc += a[k] * root2[(size_t)(k - 1024) * D_OUT + lane];
    partial[tid] = acc;
    __syncthreads();
    if (tid < 64) {
      float r4 = partial[tid] + partial[tid + 64] + partial[tid + 128] + partial[tid + 192];
      emb[(size_t)pl * D_OUT + tid] = r4 + b2[tid];
    }
  }
  // done-count; last block (of all 256) performs pooling
  __syncthreads();
  if (tid == 0) {
    __threadfence();                          // release emb writes
    int old = atomicAdd(&ctr[2], 1);          // device-scope
    flag = (old == N_POOL - 1) ? 1 : 0;
  }
  __syncthreads();
  if (flag) {
    __threadfence();                          // acquire others' emb writes
    int node = pool[tid];
    const float* xr = x + (size_t)node * D_IN;
    ew[tid] = 4.0f * xr[0] + 1.0f * xr[1] + 2.0f * xr[2];
    pls[tid] = pId[node] - 1;
    __syncthreads();
    if (tid < D_OUT) {
      float sw = 0.0f;
      for (int j = 0; j < N_POOL; j++) sw += ew[j];
      float acc = 0.0f;
      for (int j = 0; j < N_POOL; j++) acc += ew[j] * emb[(size_t)pls[j] * D_OUT + tid];
      out[tid] = acc / (sw + 1e-9f);
    }
  }
}

extern "C" void kernel_launch(void* const* d_in, const int* in_sizes, int n_in,
                              void* d_out, int out_size, void* d_ws, size_t ws_size,
                              hipStream_t stream) {
  const float* x     = (const float*)d_in[0];
  const int*   EI    = (const int*)  d_in[1];
  const int*   ET    = (const int*)  d_in[2];
  const int*   pool  = (const int*)  d_in[3];
  const float* W1    = (const float*)d_in[4];
  const float* root1 = (const float*)d_in[5];
  const float* b1    = (const float*)d_in[6];
  const float* W2    = (const float*)d_in[7];
  const float* root2 = (const float*)d_in[8];
  const float* b2    = (const float*)d_in[9];
  float* out = (float*)d_out;
  float* ws  = (float*)d_ws;

  int*      fillCtr = (int*)(ws + OFF_FILLC);
  int*      fillCtr2= (int*)(ws + OFF_FILLC2);
  unsigned* pBit    = (unsigned*)(ws + OFF_PBIT);
  unsigned* sBit    = (unsigned*)(ws + OFF_SBIT);
  int*      ctr     = (int*)(ws + OFF_CTR);
  int*      pId     = (int*)(ws + OFF_PID);
  int*      sId     = (int*)(ws + OFF_SID);
  int*      pNodes  = (int*)(ws + OFF_PNODES);
  int*      sNodes  = (int*)(ws + OFF_SNODES);
  int*      srcSlot = (int*)(ws + OFF_SRCSLOT);
  int*      eslot2  = (int*)(ws + OFF_ESLOT2);
  unsigned* agg1b   = (unsigned*)(ws + OFF_AGG1B);
  unsigned* xall    = (unsigned*)(ws + OFF_XALL);
  unsigned short* Wt = (unsigned short*)(ws + OFF_WT);
  float*    h       = ws + OFF_H;
  float*    emb     = ws + OFF_EMB;

  k_init<<<1024, 256, 0, stream>>>(pool, x, W1, root1, ws);
  k_pass1<<<(N_EDGES / 4 + 255) / 256, 256, 0, stream>>>(EI, pBit, sBit);
  k_compactS<<<(N_NODES + 255) / 256, 256, 0, stream>>>(sBit, pBit, sId, sNodes, pId, pNodes, ctr);
  k_fill<<<(N_EDGES / 4 + 255) / 256, 256, 0, stream>>>(
      EI, ET, sBit, pBit, sId, pId, fillCtr, srcSlot, fillCtr2, eslot2);
  k_gather<<<NSEG / 4, 256, 0, stream>>>(fillCtr, srcSlot, xall, ctr, agg1b);
  k_gemm1<<<dim3(CAP_S / 16, 2), 256, 0, stream>>>(
      (const unsigned short*)agg1b, (const unsigned short*)xall, Wt, b1, sNodes, ctr, h);
  k_gemm2<<<N_POOL, 256, 0, stream>>>(
      W2, root2, b2, fillCtr2, eslot2, pNodes, pId, sId, ctr, h, x, pool, emb, out);
}

// Round 10
// 206.791 us; speedup vs baseline: 4.1209x; 1.0005x over previous
//
#include <hip/hip_runtime.h>

// Problem constants (fixed by the reference setup_inputs).
#define N_NODES 50000
#define N_EDGES 1600000
#define N_REL   8
#define D_IN    128
#define D_HID   128
#define D_OUT   64
#define N_POOL  256

// Sparse dependency cone capacities (fixed seed; expected |S|~7700,
// edges-into-S ~250k; CAP_S has >1.5x margin, writes clamped).
#define CAP_S   12288
#define NSEG    (N_REL * CAP_S)     // 98304 layer-1 segments; seg = s*8 + r
#define BUCKET  32                  // layer-1 per-segment cap; deg ~ Poisson(4), P(>32)~1e-19
#define BUCKET2 32                  // layer-2 per-code cap; deg ~ Poisson(4)
#define NCODE   (N_REL * N_POOL)    // 2048 layer-2 codes; code = r*256 + pl

typedef short v8s __attribute__((ext_vector_type(8)));
typedef float v4f __attribute__((ext_vector_type(4)));

// ---- workspace layout (element offsets, 4B units) ----
// Zeroed by k_init grid-stride:
constexpr size_t OFF_FILLC  = 0;                       // NSEG int (L1 bucket counts)
constexpr size_t OFF_FILLC2 = OFF_FILLC + NSEG;        // NCODE int (L2 bucket counts)
constexpr size_t ZERO_ELEMS = OFF_FILLC2 + NCODE;      // 100,352 (div by 4)
// Zeroed by block 0 of k_init:
constexpr size_t OFF_PBIT   = ZERO_ELEMS;              // 2048 u32
constexpr size_t OFF_SBIT   = OFF_PBIT + 2048;         // 2048 u32
constexpr size_t OFF_CTR    = OFF_SBIT + 2048;         // 8 int [0]=pCount [1]=sCount
// Write-before-read:
constexpr size_t OFF_PID    = OFF_CTR + 8;             // N_NODES int
constexpr size_t OFF_SID    = OFF_PID + N_NODES;       // N_NODES int
constexpr size_t OFF_PNODES = OFF_SID + N_NODES;       // 256 int
constexpr size_t OFF_SNODES = OFF_PNODES + N_POOL;     // CAP_S int
constexpr size_t OFF_SRCSLOT= OFF_SNODES + CAP_S;      // NSEG*BUCKET int
constexpr size_t OFF_ESLOT2 = OFF_SRCSLOT + (size_t)NSEG * BUCKET;  // NCODE*BUCKET2 int
constexpr size_t OFF_AGG1B  = OFF_ESLOT2 + (size_t)NCODE * BUCKET2; // NSEG*64 u32
constexpr size_t OFF_XALL   = OFF_AGG1B + (size_t)NSEG * 64;        // N_NODES*64 u32
constexpr size_t OFF_WT     = OFF_XALL + (size_t)N_NODES * 64;      // 1152*128 bf16
constexpr size_t OFF_H      = OFF_WT + (size_t)1152 * 128 / 2;      // CAP_S*128 fp32
constexpr size_t OFF_EMB    = OFF_H + (size_t)CAP_S * D_HID;        // 256*64 fp32
constexpr size_t TOTAL_ELEMS= OFF_EMB + (size_t)N_POOL * D_OUT;     // ~52 MB

__device__ __forceinline__ void atomAddF(float* p, float v) { unsafeAtomicAdd(p, v); }

__device__ __forceinline__ unsigned short f2bf(float f) {   // RNE fp32 -> bf16
  union { float f; unsigned u; } v; v.f = f;
  unsigned r = v.u + 0x7FFFu + ((v.u >> 16) & 1u);
  return (unsigned short)(r >> 16);
}
__device__ __forceinline__ float bfLo(unsigned v) { return __uint_as_float(v << 16); }
__device__ __forceinline__ float bfHi(unsigned v) { return __uint_as_float(v & 0xFFFF0000u); }

// Fused init: zero bucket counts (grid-stride), zero+mark bitmaps + ctr
// (block 0), pack Wt (blocks 1..72), convert x->bf16 (grid-stride).
__global__ __launch_bounds__(256) void k_init(
    const int* __restrict__ pool, const float* __restrict__ x,
    const float* __restrict__ W1, const float* __restrict__ root1,
    float* __restrict__ ws) {
  unsigned* pBit = (unsigned*)(ws + OFF_PBIT);
  unsigned* sBit = (unsigned*)(ws + OFF_SBIT);
  int*      ctr  = (int*)(ws + OFF_CTR);
  unsigned* xall = (unsigned*)(ws + OFF_XALL);
  unsigned short* Wt = (unsigned short*)(ws + OFF_WT);
  int tid = threadIdx.x, bid = blockIdx.x;
  int gtid = bid * 256 + tid, gthr = gridDim.x * 256;
  int wave = tid >> 6, lane = tid & 63;

  float4 z = {0.f, 0.f, 0.f, 0.f};
  for (int i = gtid; i < (int)(ZERO_ELEMS / 4); i += gthr) ((float4*)ws)[i] = z;

  if (bid == 0) {
    for (int i = tid; i < 2048; i += 256) { pBit[i] = 0u; sBit[i] = 0u; }
    if (tid < 8) ctr[tid] = 0;
    __syncthreads();
    int node = pool[tid];
    unsigned bit = 1u << (node & 31);
    atomicOr(&pBit[node >> 5], bit);
    atomicOr(&sBit[node >> 5], bit);
  }

  int gw = (bid - 1) * 4 + wave;          // Wt pack on blocks 1..72
  if (bid >= 1 && gw < 288) {
    int kt = gw >> 3, nt = gw & 7;
    int k0 = kt * 32 + ((lane >> 4) << 3);
    int n = nt * 16 + (lane & 15);
    v8s frag;
#pragma unroll
    for (int j = 0; j < 8; j++) {
      int kg = k0 + j;
      float v = (kg < 1024) ? W1[(size_t)kg * D_HID + n]
                            : root1[(size_t)(kg - 1024) * D_HID + n];
      frag[j] = (short)f2bf(v);
    }
    ((v8s*)Wt)[gw * 64 + lane] = frag;
  }

  for (int i = gtid; i < N_NODES * 64; i += gthr) {   // x -> packed bf16
    float2 v = ((const float2*)x)[i];
    xall[i] = ((unsigned)f2bf(v.y) << 16) | f2bf(v.x);
  }
}

// Pass 1: mark sources of pooled-dst edges into sBit.
__global__ __launch_bounds__(256) void k_pass1(
    const int* __restrict__ EI, const unsigned* __restrict__ pBit, unsigned* sBit) {
  int idx = blockIdx.x * 256 + threadIdx.x;
  if (idx >= N_EDGES / 4) return;
  int4 d4 = ((const int4*)(EI + N_EDGES))[idx];
  int d[4] = {d4.x, d4.y, d4.z, d4.w};
#pragma unroll
  for (int i = 0; i < 4; i++) {
    int dst = d[i];
    if ((pBit[dst >> 5] >> (dst & 31)) & 1u) {
      int src = EI[idx * 4 + i];
      atomicOr(&sBit[src >> 5], 1u << (src & 31));
    }
  }
}

// Number S (block-aggregated atomic) and P (wave-aggregated).
__global__ __launch_bounds__(256) void k_compactS(
    const unsigned* __restrict__ sBit, const unsigned* __restrict__ pBit,
    int* sId, int* sNodes, int* pId, int* pNodes, int* ctr) {
  __shared__ int wcnt[4];
  __shared__ int sbase;
  int tid = threadIdx.x, wave = tid >> 6, lane = tid & 63;
  int node = blockIdx.x * 256 + tid;
  bool sp = (node < N_NODES) && ((sBit[node >> 5] >> (node & 31)) & 1u);
  unsigned long long m = __ballot(sp);
  if (lane == 0) wcnt[wave] = __popcll(m);
  __syncthreads();
  if (tid == 0) {
    int tot = wcnt[0] + wcnt[1] + wcnt[2] + wcnt[3];
    sbase = tot ? atomicAdd(&ctr[1], tot) : 0;
  }
  __syncthreads();
  if (sp) {
    int off = sbase;
    for (int w2 = 0; w2 < wave; w2++) off += wcnt[w2];
    int id = off + __popcll(m & ((1ull << lane) - 1ull));
    if (id < CAP_S) { sId[node] = id + 1; sNodes[id] = node; }
    else sId[node] = 0;
  }
  bool pp = (node < N_NODES) && ((pBit[node >> 5] >> (node & 31)) & 1u);
  unsigned long long pm = __ballot(pp);
  if (pm) {
    int leader = __ffsll(pm) - 1;
    int base = 0;
    if (lane == leader) base = atomicAdd(&ctr[0], __popcll(pm));
    base = __shfl(base, leader);
    if (pp) {
      int id = base + __popcll(pm & ((1ull << lane) - 1ull));
      pId[node] = id + 1;
      pNodes[id] = node;
    }
  }
}

// Fill bucket CSRs: layer-1 (dst in S -> srcSlot by seg) and layer-2
// (dst pooled -> s-local of src by code). One pass over all edges; the
// src/type int4s are only loaded when the dst-quad has at least one hit.
__global__ __launch_bounds__(256) void k_fill(
    const int* __restrict__ EI, const int* __restrict__ ET,
    const unsigned* __restrict__ sBit, const unsigned* __restrict__ pBit,
    const int* __restrict__ sId, const int* __restrict__ pId,
    int* __restrict__ fillCtr, int* __restrict__ srcSlot,
    int* __restrict__ fillCtr2, int* __restrict__ eslot2) {
  int idx = blockIdx.x * 256 + threadIdx.x;
  if (idx >= N_EDGES / 4) return;
  int4 d4 = ((const int4*)(EI + N_EDGES))[idx];
  int d[4] = {d4.x, d4.y, d4.z, d4.w};
  bool any = false;
#pragma unroll
  for (int i = 0; i < 4; i++)
    any |= ((sBit[d[i] >> 5] >> (d[i] & 31)) & 1u) != 0u;
  if (!any) return;
  int4 t4 = ((const int4*)ET)[idx];
  int4 s4 = ((const int4*)EI)[idx];
  int t[4] = {t4.x, t4.y, t4.z, t4.w};
  int s[4] = {s4.x, s4.y, s4.z, s4.w};
#pragma unroll
  for (int i = 0; i < 4; i++) {
    int dst = d[i];
    if ((sBit[dst >> 5] >> (dst & 31)) & 1u) {
      int sp = sId[dst];
      if (sp > 0) {
        int seg = ((sp - 1) << 3) + t[i];
        int slot = atomicAdd(&fillCtr[seg], 1);
        if (slot < BUCKET) srcSlot[seg * BUCKET + slot] = s[i];
      }
      if ((pBit[dst >> 5] >> (dst & 31)) & 1u) {     // pooled dst (subset of S)
        int code = t[i] * N_POOL + (pId[dst] - 1);
        int sl = sId[s[i]] - 1;                      // src is in S by construction
        if (sl >= 0) {
          int slot = atomicAdd(&fillCtr2[code], 1);
          if (slot < BUCKET2) eslot2[code * BUCKET2 + slot] = sl;
        }
      }
    }
  }
}

// Gather-reduce layer 1: one wave per segment; bf16 row gathers, 4 in flight;
// write MEAN as packed bf16. Active segments contiguous in [0, 8*sCount).
__global__ __launch_bounds__(256) void k_gather(
    const int* __restrict__ fillCtr, const int* __restrict__ srcSlot,
    const unsigned* __restrict__ xall, const int* __restrict__ ctr,
    unsigned* __restrict__ agg1b) {
  int w = (blockIdx.x << 2) + (threadIdx.x >> 6);
  if (w >= (ctr[1] << 3)) return;
  int lane = threadIdx.x & 63;
  int cnt = fillCtr[w];
  if (cnt > BUCKET) cnt = BUCKET;
  const int* slot = srcSlot + w * BUCKET;
  float a0 = 0.f, a1 = 0.f;
  int i = 0;
  for (; i + 4 <= cnt; i += 4) {
    int s0 = slot[i + 0];
    int s1 = slot[i + 1];
    int s2 = slot[i + 2];
    int s3 = slot[i + 3];
    unsigned v0 = xall[(size_t)s0 * 64 + lane];
    unsigned v1 = xall[(size_t)s1 * 64 + lane];
    unsigned v2 = xall[(size_t)s2 * 64 + lane];
    unsigned v3 = xall[(size_t)s3 * 64 + lane];
    a0 += (bfLo(v0) + bfLo(v1)) + (bfLo(v2) + bfLo(v3));
    a1 += (bfHi(v0) + bfHi(v1)) + (bfHi(v2) + bfHi(v3));
  }
  for (; i < cnt; i++) {
    unsigned v = xall[(size_t)slot[i] * 64 + lane];
    a0 += bfLo(v);
    a1 += bfHi(v);
  }
  float inv = 1.0f / fmaxf((float)cnt, 1.0f);
  agg1b[(size_t)w * 64 + lane] = ((unsigned)f2bf(a1 * inv) << 16) | f2bf(a0 * inv);
}

// Layer-1 GEMM via bf16 MFMA 16x16x32, K-split x4 + N-split x2.
__global__ __launch_bounds__(256) void k_gemm1(
    const unsigned short* __restrict__ agg1b, const unsigned short* __restrict__ xall,
    const unsigned short* __restrict__ Wt, const float* __restrict__ b1,
    const int* __restrict__ sNodes, const int* __restrict__ ctr,
    float* __restrict__ h) {
  __shared__ float red[4][16][64];           // 16 KB
  int sCount = ctr[1];
  int s0 = blockIdx.x * 16;
  if (s0 >= sCount) return;
  int colTile = blockIdx.y;                  // 0..1
  int wave = threadIdx.x >> 6, lane = threadIdx.x & 63;
  int quad = lane >> 4, mn = lane & 15;
  int srow = s0 + mn;
  int g = (srow < sCount) ? sNodes[srow] : 0;
  v4f acc[4];
#pragma unroll
  for (int i = 0; i < 4; i++) acc[i] = (v4f){0.f, 0.f, 0.f, 0.f};
  const v8s* WtF = (const v8s*)Wt;
  int kt0 = wave * 9, kt1 = kt0 + 9;
  for (int kt = kt0; kt < kt1; kt++) {
    const unsigned short* aptr;
    if (kt < 32) {                           // mean part: k = r*128 + d
      int r = kt >> 2;
      int d0 = (kt & 3) * 32 + quad * 8;
      aptr = agg1b + ((size_t)((srow << 3) + r) * 128 + d0);
    } else {                                 // root part from xall
      int d0 = (kt - 32) * 32 + quad * 8;
      aptr = xall + ((size_t)g * 128 + d0);
    }
    v8s afrag = *(const v8s*)aptr;
    const v8s* wrow = WtF + (size_t)(kt * 8 + colTile * 4) * 64 + lane;
#pragma unroll
    for (int nt = 0; nt < 4; nt++) {
      v8s bfrag = wrow[nt * 64];
      acc[nt] = __builtin_amdgcn_mfma_f32_16x16x32_bf16(afrag, bfrag, acc[nt], 0, 0, 0);
    }
  }
#pragma unroll
  for (int nt = 0; nt < 4; nt++)
#pragma unroll
    for (int reg = 0; reg < 4; reg++)
      red[wave][nt * 4 + reg][lane] = acc[nt][reg];
  __syncthreads();
  int nt2 = threadIdx.x >> 6;
  int lane2 = threadIdx.x & 63;
  int quad2 = lane2 >> 4, mn2 = lane2 & 15;
#pragma unroll
  for (int reg = 0; reg < 4; reg++) {
    int idx = nt2 * 4 + reg;
    float v = red[0][idx][lane2] + red[1][idx][lane2]
            + red[2][idx][lane2] + red[3][idx][lane2];
    int s = s0 + quad2 * 4 + reg;
    int col = colTile * 64 + nt2 * 16 + mn2;
    if (s < sCount)
      h[(size_t)s * D_HID + col] = fmaxf(v + b1[col], 0.0f);
  }
}

// Layer-2 GEMM per pooled node: gathers its own 8 code-buckets into LDS
// (mean applied in-register), then 4-way K-split GEMM. No fences — the
// pooling runs as a separate launch (coherence via launch boundary).
__global__ __launch_bounds__(256) void k_gemm2(
    const float* __restrict__ W2, const float* __restrict__ root2,
    const float* __restrict__ b2,
    const int* __restrict__ fillCtr2, const int* __restrict__ eslot2,
    const int* __restrict__ pNodes, const int* __restrict__ sId,
    const int* __restrict__ ctr, const float* __restrict__ h,
    float* __restrict__ emb) {
  __shared__ float a[N_REL * D_HID + D_HID];  // 1152
  __shared__ float partial[256];
  int pl = blockIdx.x;
  if (pl >= ctr[0]) return;
  int tid = threadIdx.x, wave = tid >> 6, lane = tid & 63;
  // gather this node's 8 relation-buckets: wave handles codes r=2w, 2w+1
#pragma unroll
  for (int rr = 0; rr < 2; rr++) {
    int r = wave * 2 + rr;
    int code = r * N_POOL + pl;
    int cnt = fillCtr2[code]; if (cnt > BUCKET2) cnt = BUCKET2;
    const int* sl = eslot2 + code * BUCKET2;
    float s0 = 0.f, s1 = 0.f;
    for (int i = 0; i < cnt; i++) {
      float2 v = ((const float2*)h)[(size_t)sl[i] * 64 + lane];
      s0 += v.x; s1 += v.y;
    }
    float inv = 1.0f / fmaxf((float)cnt, 1.0f);
    a[r * 128 + lane * 2]     = s0 * inv;
    a[r * 128 + lane * 2 + 1] = s1 * inv;
  }
  if (tid < 128) {
    int slp = sId[pNodes[pl]] - 1;
    a[1024 + tid] = h[(size_t)slp * D_HID + tid];
  }
  __syncthreads();
  int lo = wave * 288, hi = lo + 288;
  float acc = 0.0f;
  int hiW = (hi < 1024) ? hi : 1024;
#pragma unroll 4
  for (int k = lo; k < hiW; k++) acc += a[k] * W2[(size_t)k * D_OUT + lane];
  int loR = (lo > 1024) ? lo : 1024;
#pragma unroll 4
  for (int k = loR; k < hi; k++) acc += a[k] * root2[(size_t)(k - 1024) * D_OUT + lane];
  partial[tid] = acc;
  __syncthreads();
  if (tid < 64) {
    float r4 = partial[tid] + partial[tid + 64] + partial[tid + 128] + partial[tid + 192];
    emb[(size_t)pl * D_OUT + tid] = r4 + b2[tid];
  }
}

// Weighted pooling (separate launch; launch boundary = coherence).
__global__ __launch_bounds__(256) void k_pool(
    const float* __restrict__ x, const int* __restrict__ pool,
    const int* __restrict__ pId, const float* __restrict__ emb,
    float* __restrict__ out) {
  __shared__ float ew[N_POOL];
  __shared__ int pls[N_POOL];
  int tid = threadIdx.x;
  int node = pool[tid];
  const float* xr = x + (size_t)node * D_IN;
  ew[tid] = 4.0f * xr[0] + 1.0f * xr[1] + 2.0f * xr[2];
  pls[tid] = pId[node] - 1;
  __syncthreads();
  if (tid < D_OUT) {
    float sw = 0.0f;
    for (int j = 0; j < N_POOL; j++) sw += ew[j];
    float acc = 0.0f;
    for (int j = 0; j < N_POOL; j++) acc += ew[j] * emb[(size_t)pls[j] * D_OUT + tid];
    out[tid] = acc / (sw + 1e-9f);
  }
}

extern "C" void kernel_launch(void* const* d_in, const int* in_sizes, int n_in,
                              void* d_out, int out_size, void* d_ws, size_t ws_size,
                              hipStream_t stream) {
  const float* x     = (const float*)d_in[0];
  const int*   EI    = (const int*)  d_in[1];
  const int*   ET    = (const int*)  d_in[2];
  const int*   pool  = (const int*)  d_in[3];
  const float* W1    = (const float*)d_in[4];
  const float* root1 = (const float*)d_in[5];
  const float* b1    = (const float*)d_in[6];
  const float* W2    = (const float*)d_in[7];
  const float* root2 = (const float*)d_in[8];
  const float* b2    = (const float*)d_in[9];
  float* out = (float*)d_out;
  float* ws  = (float*)d_ws;

  int*      fillCtr = (int*)(ws + OFF_FILLC);
  int*      fillCtr2= (int*)(ws + OFF_FILLC2);
  unsigned* pBit    = (unsigned*)(ws + OFF_PBIT);
  unsigned* sBit    = (unsigned*)(ws + OFF_SBIT);
  int*      ctr     = (int*)(ws + OFF_CTR);
  int*      pId     = (int*)(ws + OFF_PID);
  int*      sId     = (int*)(ws + OFF_SID);
  int*      pNodes  = (int*)(ws + OFF_PNODES);
  int*      sNodes  = (int*)(ws + OFF_SNODES);
  int*      srcSlot = (int*)(ws + OFF_SRCSLOT);
  int*      eslot2  = (int*)(ws + OFF_ESLOT2);
  unsigned* agg1b   = (unsigned*)(ws + OFF_AGG1B);
  unsigned* xall    = (unsigned*)(ws + OFF_XALL);
  unsigned short* Wt = (unsigned short*)(ws + OFF_WT);
  float*    h       = ws + OFF_H;
  float*    emb     = ws + OFF_EMB;

  k_init<<<1024, 256, 0, stream>>>(pool, x, W1, root1, ws);
  k_pass1<<<(N_EDGES / 4 + 255) / 256, 256, 0, stream>>>(EI, pBit, sBit);
  k_compactS<<<(N_NODES + 255) / 256, 256, 0, stream>>>(sBit, pBit, sId, sNodes, pId, pNodes, ctr);
  k_fill<<<(N_EDGES / 4 + 255) / 256, 256, 0, stream>>>(
      EI, ET, sBit, pBit, sId, pId, fillCtr, srcSlot, fillCtr2, eslot2);
  k_gather<<<NSEG / 4, 256, 0, stream>>>(fillCtr, srcSlot, xall, ctr, agg1b);
  k_gemm1<<<dim3(CAP_S / 16, 2), 256, 0, stream>>>(
      (const unsigned short*)agg1b, (const unsigned short*)xall, Wt, b1, sNodes, ctr, h);
  k_gemm2<<<N_POOL, 256, 0, stream>>>(
      W2, root2, b2, fillCtr2, eslot2, pNodes, sId, ctr, h, emb);
  k_pool<<<1, 256, 0, stream>>>(x, pool, pId, emb, out);
}